// Round 1
// baseline (1748.992 us; speedup 1.0000x reference)
//
#include <hip/hip_runtime.h>

#define B_ 4
#define L_ 256
#define D_ 1024
#define D4_ 256
#define K_ 3
#define NL_ 3
#define MAXLEN_ 500
#define R_ 8

__device__ __forceinline__ float4 ld4(const float* p){ return *reinterpret_cast<const float4*>(p); }
__device__ __forceinline__ void st4(float* p, float4 v){ *reinterpret_cast<float4*>(p) = v; }

// ---------------------------------------------------------------------------
// Mask decode: mask is a prefix mask (lengths in [128,256]) so the first bytes
// have a deterministic pattern per dtype. Detect element stride, count truths.
// ---------------------------------------------------------------------------
__global__ void k_lengths(const unsigned char* mask, int* lengths){
  int t = threadIdx.x;
  if (t >= B_) return;
  const unsigned int* w = (const unsigned int*)mask;
  unsigned int w0 = w[0];
  int stride = 1;
  if      (w0 == 0x01010101u) stride = 1;                       // uint8 bool
  else if (w0 == 0x3F803F80u) stride = 2;                       // bf16 1.0
  else if (w0 == 0x3C003C00u) stride = 2;                       // f16 1.0
  else if (w0 == 0x3F800000u) stride = 4;                       // f32 1.0
  else if (w0 == 1u && w[1] == 1u) stride = 4;                  // int32 1
  else if (w0 == 1u && w[1] == 0u) stride = 8;                  // int64 1
  else if (w0 == 0u && w[1] == 0x3FF00000u) stride = 8;         // f64 1.0
  int c = 0;
  for (int l = 0; l < L_; l++){
    const unsigned char* e = mask + (size_t)(t*L_ + l)*stride;
    unsigned char nz = 0;
    for (int s = 0; s < stride; s++) nz |= e[s];
    c += (nz != 0) ? 1 : 0;
  }
  lengths[t] = c;
}

// ---------------------------------------------------------------------------
// PE rows actually used: idx = MAXLEN + i - j in [245,755] -> t = idx-245 in [0,510]
// position = MAXLEN - (245+t) = 255 - t
// ---------------------------------------------------------------------------
__global__ void k_pe(float* pe){
  int t = blockIdx.x;                 // 0..510
  float posv = (float)(255 - t);
  const float c = -9.210340371976184f / (float)D_;   // -ln(10000)/D
  for (int m = threadIdx.x; m < D_/2; m += blockDim.x){
    float div = expf((float)(2*m) * c);
    float val = posv * div;
    pe[(size_t)t*D_ + 2*m]     = sinf(val);
    pe[(size_t)t*D_ + 2*m + 1] = cosf(val);
  }
}

// ---------------------------------------------------------------------------
// Generic C[M,N] = A[M,Kd] @ W[N,Kd]^T + bias[N].  64x64 tile, BK=32.
// Transposed LDS so inner loop is two ds_read_b128 + 16 fmac.
// ---------------------------------------------------------------------------
#define GBM 64
#define GBN 64
#define GBK 32
__global__ __launch_bounds__(256) void k_gemm(const float* __restrict__ A,
                                              const float* __restrict__ Wt,
                                              const float* __restrict__ bias,
                                              float* __restrict__ C,
                                              int M, int N, int Kd)
{
  __shared__ __align__(16) float As[GBK][GBM+4];   // [kk][row], stride 68
  __shared__ __align__(16) float Ws[GBK][GBN+4];
  int tid = threadIdx.x;
  int trow = tid >> 4, tcol = tid & 15;
  int row0 = blockIdx.x * GBM, col0 = blockIdx.y * GBN;
  float acc[4][4] = {};
  for (int k0 = 0; k0 < Kd; k0 += GBK){
    for (int idx = tid; idx < GBM*GBK; idx += 256){
      int r = idx >> 5, kk = idx & 31;
      int row = row0 + r;
      As[kk][r] = (row < M) ? A[(size_t)row*Kd + k0 + kk] : 0.f;
    }
    for (int idx = tid; idx < GBN*GBK; idx += 256){
      int r = idx >> 5, kk = idx & 31;
      Ws[kk][r] = Wt[(size_t)(col0 + r)*Kd + k0 + kk];
    }
    __syncthreads();
    #pragma unroll
    for (int kk = 0; kk < GBK; kk++){
      float4 a = ld4(&As[kk][trow*4]);
      float4 wv4 = ld4(&Ws[kk][tcol*4]);
      float av[4] = {a.x,a.y,a.z,a.w};
      float wv[4] = {wv4.x,wv4.y,wv4.z,wv4.w};
      #pragma unroll
      for (int ri=0;ri<4;ri++)
        #pragma unroll
        for (int ci=0;ci<4;ci++)
          acc[ri][ci] += av[ri]*wv[ci];
    }
    __syncthreads();
  }
  float4 bs = ld4(&bias[col0 + tcol*4]);
  float bv[4] = {bs.x,bs.y,bs.z,bs.w};
  #pragma unroll
  for (int ri=0;ri<4;ri++){
    int row = row0 + trow*4 + ri;
    if (row < M){
      float4 o = make_float4(acc[ri][0]+bv[0], acc[ri][1]+bv[1],
                             acc[ri][2]+bv[2], acc[ri][3]+bv[3]);
      st4(&C[(size_t)row*N + col0 + tcol*4], o);
    }
  }
}

// ---------------------------------------------------------------------------
// cumsum: f_cum[b,l] = sum_{l'<l} cum', b_cum[b,j] = sum_{l'>j} cum',
// where cum' is cum zeroed at positions l < len (mask true -> 0).
// ---------------------------------------------------------------------------
__global__ void k_cumsum(const float* __restrict__ cum, const int* __restrict__ lengths,
                         float* __restrict__ f_cum, float* __restrict__ b_cum)
{
  int b = blockIdx.x, k = threadIdx.x;
  int len = lengths[b];
  const float* src = cum + (size_t)b*L_*D4_ + k;
  float run = 0.f;
  for (int l = 0; l < L_; l++){
    f_cum[((size_t)b*L_ + l)*D4_ + k] = run;
    if (l >= len) run += src[(size_t)l*D4_];
  }
  float total = run;
  run = 0.f;
  for (int l = 0; l < L_; l++){
    if (l >= len) run += src[(size_t)l*D4_];
    b_cum[((size_t)b*L_ + l)*D4_ + k] = total - run;
  }
}

// ---------------------------------------------------------------------------
// Conv layer as implicit GEMM. Block: 64 l-rows x 64 o-cols, K-loop over
// 16 chunks of 64 channels x 3 taps. Input masked by lengths, zero pad l.
// ---------------------------------------------------------------------------
__global__ __launch_bounds__(256) void k_conv(const float* __restrict__ hin,
                                              const float* __restrict__ cw,
                                              const float* __restrict__ cb,
                                              const int* __restrict__ lengths,
                                              float* __restrict__ y, int layer)
{
  __shared__ __align__(16) float As[64][68];     // [cc][i], i = l - (l0-1), 0..65
  __shared__ __align__(16) float Wsh[192][68];   // [cc*3+t][oo]
  int tid = threadIdx.x;
  int trow = tid >> 4, tcol = tid & 15;
  int bx = blockIdx.x;
  int b = bx >> 2, l0 = (bx & 3) * 64;
  int o0 = blockIdx.y * 64;
  int len = lengths[b];
  const float* wbase = cw + (size_t)layer*D_*D_*K_;
  float acc[4][4] = {};
  for (int c0 = 0; c0 < D_; c0 += 64){
    for (int idx = tid; idx < 66*64; idx += 256){
      int i = idx >> 6, cc = idx & 63;
      int l = l0 - 1 + i;
      float v = 0.f;
      if (l >= 0 && l < L_ && l < len) v = hin[((size_t)b*L_ + l)*D_ + c0 + cc];
      As[cc][i] = v;
    }
    for (int idx = tid; idx < 64*192; idx += 256){
      int oo = idx / 192, r = idx % 192;   // r = cc*3+t, contiguous in global
      Wsh[r][oo] = wbase[(size_t)(o0+oo)*D_*K_ + (size_t)c0*K_ + r];
    }
    __syncthreads();
    #pragma unroll 2
    for (int cc = 0; cc < 64; cc++){
      float4 alo = ld4(&As[cc][trow*4]);
      float2 ahi = *reinterpret_cast<const float2*>(&As[cc][trow*4+4]);
      float a[6] = {alo.x, alo.y, alo.z, alo.w, ahi.x, ahi.y};
      #pragma unroll
      for (int t = 0; t < 3; t++){
        float4 w4 = ld4(&Wsh[cc*3+t][tcol*4]);
        float wv[4] = {w4.x,w4.y,w4.z,w4.w};
        #pragma unroll
        for (int ri=0;ri<4;ri++)
          #pragma unroll
          for (int ci=0;ci<4;ci++)
            acc[ri][ci] += a[ri+t]*wv[ci];
      }
    }
    __syncthreads();
  }
  const float* cbl = cb + (size_t)layer*D_;
  float4 bs = ld4(&cbl[o0 + tcol*4]);
  float bv[4] = {bs.x,bs.y,bs.z,bs.w};
  #pragma unroll
  for (int ri=0;ri<4;ri++){
    int l = l0 + trow*4 + ri;
    float4 o = make_float4(acc[ri][0]+bv[0], acc[ri][1]+bv[1],
                           acc[ri][2]+bv[2], acc[ri][3]+bv[3]);
    st4(&y[((size_t)b*L_ + l)*D_ + o0 + tcol*4], o);
  }
}

// ---------------------------------------------------------------------------
// LayerNorm(D=1024, no affine) + tanh, one block per (b,l).
// ---------------------------------------------------------------------------
__global__ __launch_bounds__(256) void k_ln_tanh(const float* __restrict__ y,
                                                 float* __restrict__ hout)
{
  __shared__ float red[16];
  int n = blockIdx.x;
  int tid = threadIdx.x, lane = tid & 63, wid = tid >> 6;
  const float* yr = y + (size_t)n*D_;
  float4 v = ld4(&yr[tid*4]);
  float s = v.x+v.y+v.z+v.w;
  #pragma unroll
  for (int m=1;m<64;m<<=1) s += __shfl_xor(s, m);
  if (lane == 0) red[wid] = s;
  __syncthreads();
  float mu = (red[0]+red[1]+red[2]+red[3]) * (1.f/D_);
  float d0=v.x-mu, d1=v.y-mu, d2=v.z-mu, d3=v.w-mu;
  float ss = d0*d0+d1*d1+d2*d2+d3*d3;
  #pragma unroll
  for (int m=1;m<64;m<<=1) ss += __shfl_xor(ss, m);
  if (lane == 0) red[8+wid] = ss;
  __syncthreads();
  float var = (red[8]+red[9]+red[10]+red[11]) * (1.f/D_);
  float rstd = rsqrtf(var + 1e-5f);
  float4 o = make_float4(tanhf(d0*rstd), tanhf(d1*rstd), tanhf(d2*rstd), tanhf(d3*rstd));
  st4(&hout[(size_t)n*D_ + tid*4], o);
}

// ---------------------------------------------------------------------------
// Pair kernel: one wave per (b,i,j). hid(256) -> LN*g+b -> tanh -> Wo(8x256)
// -> tanh(x/7.5)*7.5, vis mask, write logits (+root on diagonal).
// ---------------------------------------------------------------------------
__global__ __launch_bounds__(256) void k_pairs(const float* __restrict__ c_lin,
                                               const float* __restrict__ p_lin,
                                               const float* __restrict__ f_cum,
                                               const float* __restrict__ b_cum,
                                               const float* __restrict__ pos_tab,
                                               const float* __restrict__ ln_g,
                                               const float* __restrict__ ln_b,
                                               const float* __restrict__ Wo,
                                               const float* __restrict__ bo,
                                               const int* __restrict__ lengths,
                                               float* __restrict__ out)
{
  int tid = threadIdx.x;
  int wid = tid >> 6, lane = tid & 63;
  unsigned p = blockIdx.x * 4u + wid;
  int b = p >> 16;
  int i = (p >> 8) & 255;
  int j = p & 255;
  int k = lane * 4;
  float4 cv = ld4(&c_lin[((size_t)b*L_ + i)*D4_ + k]);
  float4 pv = ld4(&p_lin[((size_t)b*L_ + j)*D4_ + k]);
  float4 fv = ld4(&f_cum[((size_t)b*L_ + i)*D4_ + k]);
  float4 bv = ld4(&b_cum[((size_t)b*L_ + j)*D4_ + k]);
  float4 rv = ld4(&pos_tab[(size_t)(i - j + 255)*D4_ + k]);
  float h0 = cv.x+pv.x+fv.x-bv.x+rv.x;
  float h1 = cv.y+pv.y+fv.y-bv.y+rv.y;
  float h2 = cv.z+pv.z+fv.z-bv.z+rv.z;
  float h3 = cv.w+pv.w+fv.w-bv.w+rv.w;
  float s = h0+h1+h2+h3;
  #pragma unroll
  for (int m=1;m<64;m<<=1) s += __shfl_xor(s, m);
  float mu = s * (1.f/D4_);
  float d0=h0-mu, d1=h1-mu, d2=h2-mu, d3=h3-mu;
  float ss = d0*d0+d1*d1+d2*d2+d3*d3;
  #pragma unroll
  for (int m=1;m<64;m<<=1) ss += __shfl_xor(ss, m);
  float rstd = rsqrtf(ss*(1.f/D4_) + 1e-5f);
  float4 g  = ld4(&ln_g[k]);
  float4 bt = ld4(&ln_b[k]);
  float v0 = tanhf(d0*rstd*g.x + bt.x);
  float v1 = tanhf(d1*rstd*g.y + bt.y);
  float v2 = tanhf(d2*rstd*g.z + bt.z);
  float v3 = tanhf(d3*rstd*g.w + bt.w);
  float part[8];
  #pragma unroll
  for (int r=0;r<8;r++){
    float4 w = ld4(&Wo[r*D4_ + k]);
    part[r] = v0*w.x + v1*w.y + v2*w.z + v3*w.w;
  }
  #pragma unroll
  for (int m=1;m<64;m<<=1){
    #pragma unroll
    for (int r=0;r<8;r++) part[r] += __shfl_xor(part[r], m);
  }
  if (lane == 0){
    int len = lengths[b];
    bool vis = (i < len) && (j < len);
    float o[8];
    #pragma unroll
    for (int r=0;r<8;r++){
      float sc = (part[r] + bo[r]) * (1.f/7.5f);
      o[r] = vis ? tanhf(sc)*7.5f : -64.f;
    }
    float* lp = out + (((size_t)b*L_ + i)*L_ + j)*R_;
    st4(lp,     make_float4(o[0],o[1],o[2],o[3]));
    st4(lp + 4, make_float4(o[4],o[5],o[6],o[7]));
    if (i == j){
      float* rp = out + (size_t)B_*L_*L_*R_ + ((size_t)b*L_ + i)*R_;
      st4(rp,     make_float4(o[0],o[1],o[2],o[3]));
      st4(rp + 4, make_float4(o[4],o[5],o[6],o[7]));
    }
  }
}

// ---------------------------------------------------------------------------
extern "C" void kernel_launch(void* const* d_in, const int* in_sizes, int n_in,
                              void* d_out, int out_size, void* d_ws, size_t ws_size,
                              hipStream_t stream)
{
  const float* X      = (const float*)d_in[0];
  const float* conv_w = (const float*)d_in[1];
  const float* conv_b = (const float*)d_in[2];
  const float* Wc     = (const float*)d_in[3];
  const float* bc     = (const float*)d_in[4];
  const float* Wp     = (const float*)d_in[5];
  const float* bp     = (const float*)d_in[6];
  const float* Wcum   = (const float*)d_in[7];
  const float* bcum   = (const float*)d_in[8];
  const float* Wr     = (const float*)d_in[9];
  const float* br     = (const float*)d_in[10];
  const float* ln_g   = (const float*)d_in[11];
  const float* ln_b   = (const float*)d_in[12];
  const float* Wo     = (const float*)d_in[13];
  const float* bo     = (const float*)d_in[14];
  const unsigned char* mask = (const unsigned char*)d_in[15];
  float* out = (float*)d_out;

  float* W = (float*)d_ws;
  int* lengths = (int*)d_ws;
  size_t off = 16;
  float* cum     = W + off; off += 262144;
  float* f_cum   = W + off; off += 262144;
  float* b_cum   = W + off; off += 262144;
  float* c_lin   = W + off; off += 262144;
  float* p_lin   = W + off; off += 262144;
  float* pos_tab = W + off; off += 511*256;
  float* pe_sub  = W + off; off += 511*1024;
  float* ybuf    = W + off; off += 1048576;
  float* h_a     = W + off; off += 1048576;
  float* h_b     = W + off; off += 1048576;

  float* h_out = out + (size_t)B_*L_*L_*R_ + (size_t)B_*L_*R_;  // h goes to d_out tail

  k_lengths<<<1, 64, 0, stream>>>(mask, lengths);
  k_pe<<<511, 256, 0, stream>>>(pe_sub);

  // cum = X @ Wcum^T + bcum   (masking applied inside k_cumsum)
  k_gemm<<<dim3(16,4), 256, 0, stream>>>(X, Wcum, bcum, cum, B_*L_, D4_, D_);
  k_cumsum<<<B_, 256, 0, stream>>>(cum, lengths, f_cum, b_cum);

  // conv stack
  k_conv<<<dim3(16,16), 256, 0, stream>>>(X,   conv_w, conv_b, lengths, ybuf, 0);
  k_ln_tanh<<<B_*L_, 256, 0, stream>>>(ybuf, h_a);
  k_conv<<<dim3(16,16), 256, 0, stream>>>(h_a, conv_w, conv_b, lengths, ybuf, 1);
  k_ln_tanh<<<B_*L_, 256, 0, stream>>>(ybuf, h_b);
  k_conv<<<dim3(16,16), 256, 0, stream>>>(h_b, conv_w, conv_b, lengths, ybuf, 2);
  k_ln_tanh<<<B_*L_, 256, 0, stream>>>(ybuf, h_out);

  // linears
  k_gemm<<<dim3(16,4), 256, 0, stream>>>(h_out,  Wc, bc, c_lin,  B_*L_, D4_, D_);
  k_gemm<<<dim3(16,4), 256, 0, stream>>>(h_out,  Wp, bp, p_lin,  B_*L_, D4_, D_);
  k_gemm<<<dim3(8,4),  256, 0, stream>>>(pe_sub, Wr, br, pos_tab, 511,  D4_, D_);

  // pair kernel: logits + root
  k_pairs<<<(B_*L_*L_)/4, 256, 0, stream>>>(c_lin, p_lin, f_cum, b_cum, pos_tab,
                                            ln_g, ln_b, Wo, bo, lengths, out);
}

// Round 2
// 604.985 us; speedup vs baseline: 2.8910x; 2.8910x over previous
//
#include <hip/hip_runtime.h>

#define B_ 4
#define L_ 256
#define D_ 1024
#define D4_ 256
#define K_ 3
#define NL_ 3
#define MAXLEN_ 500
#define R_ 8

typedef __attribute__((ext_vector_type(8))) __bf16 bf16x8;
typedef __attribute__((ext_vector_type(4))) __bf16 bf16x4;
typedef __attribute__((ext_vector_type(4))) float f32x4;

__device__ __forceinline__ float4 ld4(const float* p){ return *reinterpret_cast<const float4*>(p); }
__device__ __forceinline__ void st4(float* p, float4 v){ *reinterpret_cast<float4*>(p) = v; }

// ---------------------------------------------------------------------------
// Mask decode (prefix mask, lengths in [128,256]): sniff dtype, count truths.
// ---------------------------------------------------------------------------
__global__ void k_lengths(const unsigned char* mask, int* lengths){
  int t = threadIdx.x;
  if (t >= B_) return;
  const unsigned int* w = (const unsigned int*)mask;
  unsigned int w0 = w[0];
  int stride = 1;
  if      (w0 == 0x01010101u) stride = 1;
  else if (w0 == 0x3F803F80u) stride = 2;
  else if (w0 == 0x3C003C00u) stride = 2;
  else if (w0 == 0x3F800000u) stride = 4;
  else if (w0 == 1u && w[1] == 1u) stride = 4;
  else if (w0 == 1u && w[1] == 0u) stride = 8;
  else if (w0 == 0u && w[1] == 0x3FF00000u) stride = 8;
  int c = 0;
  for (int l = 0; l < L_; l++){
    const unsigned char* e = mask + (size_t)(t*L_ + l)*stride;
    unsigned char nz = 0;
    for (int s = 0; s < stride; s++) nz |= e[s];
    c += (nz != 0) ? 1 : 0;
  }
  lengths[t] = c;
}

// ---------------------------------------------------------------------------
// PE rows used: t = i-j+255 in [0,510], position = 255 - t. Output bf16.
// ---------------------------------------------------------------------------
__global__ void k_pe(__bf16* pe){
  int t = blockIdx.x;
  float posv = (float)(255 - t);
  const float c = -9.210340371976184f / (float)D_;
  for (int m = threadIdx.x; m < D_/2; m += blockDim.x){
    float div = expf((float)(2*m) * c);
    float val = posv * div;
    pe[((size_t)t<<10) + 2*m]     = (__bf16)sinf(val);
    pe[((size_t)t<<10) + 2*m + 1] = (__bf16)cosf(val);
  }
}

// ---------------------------------------------------------------------------
// Prep: X f32 -> bf16 unmasked (for cum GEMM) + masked (conv0 input)
// ---------------------------------------------------------------------------
__global__ void k_prep_x(const float* __restrict__ X, const int* __restrict__ lengths,
                         __bf16* __restrict__ xu, __bf16* __restrict__ xm){
  int idx = blockIdx.x*256 + threadIdx.x;     // 131072 threads x 8 elems
  int row = idx >> 7, c8 = (idx & 127) << 3;
  int b = row >> 8, l = row & 255;
  bool keep = l < lengths[b];
  const float* src = X + ((size_t)row << 10) + c8;
  bf16x8 u, m;
  #pragma unroll
  for (int e = 0; e < 8; e++){
    float f = src[e];
    u[e] = (__bf16)f;
    m[e] = keep ? (__bf16)f : (__bf16)0.f;
  }
  *reinterpret_cast<bf16x8*>(xu + ((size_t)row<<10) + c8) = u;
  *reinterpret_cast<bf16x8*>(xm + ((size_t)row<<10) + c8) = m;
}

// ---------------------------------------------------------------------------
// Prep: conv_w [L][O][C][T] f32 -> Wbc [L][T][O][C] bf16 (t-major)
// ---------------------------------------------------------------------------
__global__ void k_prep_convw(const float* __restrict__ cw, __bf16* __restrict__ wbc){
  int idx = blockIdx.x*256 + threadIdx.x;     // 3*1024*256 threads
  int layer = idx / 262144;
  int rem = idx & 262143;
  int o = rem >> 8, c4 = (rem & 255) << 2;
  const float* src = cw + (((size_t)layer*1024 + o)*1024 + c4)*3;
  float4 f0 = ld4(src), f1 = ld4(src+4), f2 = ld4(src+8);
  float tv[3][4] = {
    {f0.x, f0.w, f1.z, f2.y},
    {f0.y, f1.x, f1.w, f2.z},
    {f0.z, f1.y, f2.x, f2.w}
  };
  #pragma unroll
  for (int t = 0; t < 3; t++){
    bf16x4 v;
    #pragma unroll
    for (int e = 0; e < 4; e++) v[e] = (__bf16)tv[t][e];
    *reinterpret_cast<bf16x4*>(wbc + ((size_t)(layer*3+t)*1024 + o)*1024 + c4) = v;
  }
}

// ---------------------------------------------------------------------------
// Prep: 4 linear weight matrices [256][1024] f32 -> bf16 (same layout)
// ---------------------------------------------------------------------------
__global__ void k_prep_w(const float* __restrict__ w0, const float* __restrict__ w1,
                         const float* __restrict__ w2, const float* __restrict__ w3,
                         __bf16* __restrict__ o0, __bf16* __restrict__ o1,
                         __bf16* __restrict__ o2, __bf16* __restrict__ o3){
  const float* src; __bf16* dst;
  switch (blockIdx.y){
    case 0: src = w0; dst = o0; break;
    case 1: src = w1; dst = o1; break;
    case 2: src = w2; dst = o2; break;
    default: src = w3; dst = o3; break;
  }
  int idx = blockIdx.x*256 + threadIdx.x;     // 32768 threads x 8
  const float* p = src + (size_t)idx*8;
  bf16x8 v;
  #pragma unroll
  for (int e = 0; e < 8; e++) v[e] = (__bf16)p[e];
  *reinterpret_cast<bf16x8*>(dst + (size_t)idx*8) = v;
}

// ---------------------------------------------------------------------------
// Generic MFMA GEMM: C[M,N] = A[M,Kd]bf16 @ B[N,Kd]^T bf16 + bias. 64x64 tile.
// 4 waves, each 32x32 via 2x2 mfma_f32_16x16x32_bf16 frags. XOR-swizzled LDS.
// ---------------------------------------------------------------------------
__global__ __launch_bounds__(256) void k_gemm_mfma(const __bf16* __restrict__ A,
                                                   const __bf16* __restrict__ Bw,
                                                   const float* __restrict__ bias,
                                                   float* __restrict__ C,
                                                   int M, int N, int Kd)
{
  __shared__ __align__(16) __bf16 As[64][64];
  __shared__ __align__(16) __bf16 Bs[64][64];
  int tid = threadIdx.x;
  int lane = tid & 63, wave = tid >> 6;
  int wm = (wave >> 1) << 5, wn = (wave & 1) << 5;
  int row0 = blockIdx.x << 6, col0 = blockIdx.y << 6;
  f32x4 acc[2][2] = {};
  for (int k0 = 0; k0 < Kd; k0 += 64){
    for (int idx = tid; idx < 512; idx += 256){
      int r = idx >> 3, c = idx & 7;
      int row = row0 + r;
      bf16x8 v = {};
      if (row < M) v = *reinterpret_cast<const bf16x8*>(A + (size_t)row*Kd + k0 + (c<<3));
      *reinterpret_cast<bf16x8*>(&As[r][(c ^ (r & 7)) << 3]) = v;
    }
    for (int idx = tid; idx < 512; idx += 256){
      int r = idx >> 3, c = idx & 7;
      bf16x8 v = *reinterpret_cast<const bf16x8*>(Bw + (size_t)(col0 + r)*Kd + k0 + (c<<3));
      *reinterpret_cast<bf16x8*>(&Bs[r][(c ^ (r & 7)) << 3]) = v;
    }
    __syncthreads();
    #pragma unroll
    for (int kk = 0; kk < 2; kk++){
      int kc = (kk << 2) + (lane >> 4);
      int ra0 = wm + (lane & 15), ra1 = ra0 + 16;
      int rb0 = wn + (lane & 15), rb1 = rb0 + 16;
      bf16x8 a0 = *reinterpret_cast<const bf16x8*>(&As[ra0][(kc ^ (ra0 & 7)) << 3]);
      bf16x8 a1 = *reinterpret_cast<const bf16x8*>(&As[ra1][(kc ^ (ra1 & 7)) << 3]);
      bf16x8 b0 = *reinterpret_cast<const bf16x8*>(&Bs[rb0][(kc ^ (rb0 & 7)) << 3]);
      bf16x8 b1 = *reinterpret_cast<const bf16x8*>(&Bs[rb1][(kc ^ (rb1 & 7)) << 3]);
      acc[0][0] = __builtin_amdgcn_mfma_f32_16x16x32_bf16(a0, b0, acc[0][0], 0, 0, 0);
      acc[0][1] = __builtin_amdgcn_mfma_f32_16x16x32_bf16(a0, b1, acc[0][1], 0, 0, 0);
      acc[1][0] = __builtin_amdgcn_mfma_f32_16x16x32_bf16(a1, b0, acc[1][0], 0, 0, 0);
      acc[1][1] = __builtin_amdgcn_mfma_f32_16x16x32_bf16(a1, b1, acc[1][1], 0, 0, 0);
    }
    __syncthreads();
  }
  #pragma unroll
  for (int mi = 0; mi < 2; mi++)
    #pragma unroll
    for (int ni = 0; ni < 2; ni++){
      int col = col0 + wn + (ni << 4) + (lane & 15);
      float bv = bias[col];
      #pragma unroll
      for (int e = 0; e < 4; e++){
        int row = row0 + wm + (mi << 4) + ((lane >> 4) << 2) + e;
        if (row < M) C[(size_t)row*N + col] = acc[mi][ni][e] + bv;
      }
    }
}

// ---------------------------------------------------------------------------
// Conv layer as 3 shifted MFMA GEMMs (k = t-major). 64 l-rows x 64 o-cols,
// halo rows staged once per 64-channel chunk and shared by the 3 taps.
// Input hb is pre-masked bf16. Wbc is [layer][t][o][c] bf16.
// ---------------------------------------------------------------------------
__global__ __launch_bounds__(256) void k_conv_mfma(const __bf16* __restrict__ hb,
                                                   const __bf16* __restrict__ wbc,
                                                   const float* __restrict__ cb,
                                                   float* __restrict__ y, int layer)
{
  __shared__ __align__(16) __bf16 As[66][64];
  __shared__ __align__(16) __bf16 Bs[3][64][64];
  int tid = threadIdx.x;
  int lane = tid & 63, wave = tid >> 6;
  int wm = (wave >> 1) << 5, wn = (wave & 1) << 5;
  int bx = blockIdx.x;
  int b = bx >> 2, l0 = (bx & 3) << 6;
  int o0 = blockIdx.y << 6;
  f32x4 acc[2][2] = {};
  for (int c0 = 0; c0 < D_; c0 += 64){
    for (int idx = tid; idx < 528; idx += 256){
      int r = idx >> 3, c = idx & 7;
      int l = l0 - 1 + r;
      bf16x8 v = {};
      if (l >= 0 && l < L_)
        v = *reinterpret_cast<const bf16x8*>(hb + (((size_t)(b<<8) + l) << 10) + c0 + (c<<3));
      *reinterpret_cast<bf16x8*>(&As[r][(c ^ (r & 7)) << 3]) = v;
    }
    for (int idx = tid; idx < 1536; idx += 256){
      int t = idx >> 9, r = (idx >> 3) & 63, c = idx & 7;
      bf16x8 v = *reinterpret_cast<const bf16x8*>(
          wbc + ((size_t)((layer*3 + t) << 10) + o0 + r)*1024 + c0 + (c<<3));
      *reinterpret_cast<bf16x8*>(&Bs[t][r][(c ^ (r & 7)) << 3]) = v;
    }
    __syncthreads();
    #pragma unroll
    for (int t = 0; t < 3; t++){
      #pragma unroll
      for (int kk = 0; kk < 2; kk++){
        int kc = (kk << 2) + (lane >> 4);
        int ra0 = wm + (lane & 15) + t, ra1 = ra0 + 16;
        int rb0 = wn + (lane & 15),     rb1 = rb0 + 16;
        bf16x8 a0 = *reinterpret_cast<const bf16x8*>(&As[ra0][(kc ^ (ra0 & 7)) << 3]);
        bf16x8 a1 = *reinterpret_cast<const bf16x8*>(&As[ra1][(kc ^ (ra1 & 7)) << 3]);
        bf16x8 b0 = *reinterpret_cast<const bf16x8*>(&Bs[t][rb0][(kc ^ (rb0 & 7)) << 3]);
        bf16x8 b1 = *reinterpret_cast<const bf16x8*>(&Bs[t][rb1][(kc ^ (rb1 & 7)) << 3]);
        acc[0][0] = __builtin_amdgcn_mfma_f32_16x16x32_bf16(a0, b0, acc[0][0], 0, 0, 0);
        acc[0][1] = __builtin_amdgcn_mfma_f32_16x16x32_bf16(a0, b1, acc[0][1], 0, 0, 0);
        acc[1][0] = __builtin_amdgcn_mfma_f32_16x16x32_bf16(a1, b0, acc[1][0], 0, 0, 0);
        acc[1][1] = __builtin_amdgcn_mfma_f32_16x16x32_bf16(a1, b1, acc[1][1], 0, 0, 0);
      }
    }
    __syncthreads();
  }
  const float* cbl = cb + ((size_t)layer << 10);
  #pragma unroll
  for (int mi = 0; mi < 2; mi++)
    #pragma unroll
    for (int ni = 0; ni < 2; ni++){
      int col = o0 + wn + (ni << 4) + (lane & 15);
      float bv = cbl[col];
      #pragma unroll
      for (int e = 0; e < 4; e++){
        int rowl = wm + (mi << 4) + ((lane >> 4) << 2) + e;
        y[(((size_t)(b<<8) + l0 + rowl) << 10) + col] = acc[mi][ni][e] + bv;
      }
    }
}

// ---------------------------------------------------------------------------
// cumsum over masked cum (f32)
// ---------------------------------------------------------------------------
__global__ void k_cumsum(const float* __restrict__ cum, const int* __restrict__ lengths,
                         float* __restrict__ f_cum, float* __restrict__ b_cum)
{
  int b = blockIdx.x, k = threadIdx.x;
  int len = lengths[b];
  const float* src = cum + (size_t)b*L_*D4_ + k;
  float run = 0.f;
  for (int l = 0; l < L_; l++){
    f_cum[((size_t)b*L_ + l)*D4_ + k] = run;
    if (l >= len) run += src[(size_t)l*D4_];
  }
  float total = run;
  run = 0.f;
  for (int l = 0; l < L_; l++){
    if (l >= len) run += src[(size_t)l*D4_];
    b_cum[((size_t)b*L_ + l)*D4_ + k] = total - run;
  }
}

// ---------------------------------------------------------------------------
// LN(1024)+tanh. mid: bf16 masked out (next conv input).
// fin: f32 h to d_out + bf16 unmasked (c_lin/p_lin input).
// ---------------------------------------------------------------------------
__device__ __forceinline__ void ln_core(const float* yr, int tid, int lane, int wid,
                                        float* red, float4& v, float& mu, float& rstd){
  v = ld4(&yr[tid*4]);
  float s = v.x+v.y+v.z+v.w;
  #pragma unroll
  for (int m=1;m<64;m<<=1) s += __shfl_xor(s, m);
  if (lane == 0) red[wid] = s;
  __syncthreads();
  mu = (red[0]+red[1]+red[2]+red[3]) * (1.f/D_);
  float d0=v.x-mu, d1=v.y-mu, d2=v.z-mu, d3=v.w-mu;
  float ss = d0*d0+d1*d1+d2*d2+d3*d3;
  #pragma unroll
  for (int m=1;m<64;m<<=1) ss += __shfl_xor(ss, m);
  if (lane == 0) red[8+wid] = ss;
  __syncthreads();
  rstd = rsqrtf((red[8]+red[9]+red[10]+red[11]) * (1.f/D_) + 1e-5f);
}

__global__ __launch_bounds__(256) void k_ln_tanh_mid(const float* __restrict__ y,
                                                     const int* __restrict__ lengths,
                                                     __bf16* __restrict__ hb)
{
  __shared__ float red[16];
  int n = blockIdx.x;
  int tid = threadIdx.x, lane = tid & 63, wid = tid >> 6;
  float4 v; float mu, rstd;
  ln_core(y + (size_t)n*D_, tid, lane, wid, red, v, mu, rstd);
  int l = n & 255, b = n >> 8;
  float keep = (l < lengths[b]) ? 1.f : 0.f;
  bf16x4 o;
  o[0] = (__bf16)(tanhf((v.x-mu)*rstd) * keep);
  o[1] = (__bf16)(tanhf((v.y-mu)*rstd) * keep);
  o[2] = (__bf16)(tanhf((v.z-mu)*rstd) * keep);
  o[3] = (__bf16)(tanhf((v.w-mu)*rstd) * keep);
  *reinterpret_cast<bf16x4*>(hb + ((size_t)n<<10) + tid*4) = o;
}

__global__ __launch_bounds__(256) void k_ln_tanh_fin(const float* __restrict__ y,
                                                     float* __restrict__ hf,
                                                     __bf16* __restrict__ hb)
{
  __shared__ float red[16];
  int n = blockIdx.x;
  int tid = threadIdx.x, lane = tid & 63, wid = tid >> 6;
  float4 v; float mu, rstd;
  ln_core(y + (size_t)n*D_, tid, lane, wid, red, v, mu, rstd);
  float t0 = tanhf((v.x-mu)*rstd), t1 = tanhf((v.y-mu)*rstd);
  float t2 = tanhf((v.z-mu)*rstd), t3 = tanhf((v.w-mu)*rstd);
  st4(&hf[((size_t)n<<10) + tid*4], make_float4(t0,t1,t2,t3));
  bf16x4 o; o[0]=(__bf16)t0; o[1]=(__bf16)t1; o[2]=(__bf16)t2; o[3]=(__bf16)t3;
  *reinterpret_cast<bf16x4*>(hb + ((size_t)n<<10) + tid*4) = o;
}

// ---------------------------------------------------------------------------
// Pair kernel: one wave per (b,i,j).
// ---------------------------------------------------------------------------
__global__ __launch_bounds__(256) void k_pairs(const float* __restrict__ c_lin,
                                               const float* __restrict__ p_lin,
                                               const float* __restrict__ f_cum,
                                               const float* __restrict__ b_cum,
                                               const float* __restrict__ pos_tab,
                                               const float* __restrict__ ln_g,
                                               const float* __restrict__ ln_b,
                                               const float* __restrict__ Wo,
                                               const float* __restrict__ bo,
                                               const int* __restrict__ lengths,
                                               float* __restrict__ out)
{
  int tid = threadIdx.x;
  int wid = tid >> 6, lane = tid & 63;
  unsigned p = blockIdx.x * 4u + wid;
  int b = p >> 16;
  int i = (p >> 8) & 255;
  int j = p & 255;
  int k = lane * 4;
  float4 cv = ld4(&c_lin[((size_t)b*L_ + i)*D4_ + k]);
  float4 pv = ld4(&p_lin[((size_t)b*L_ + j)*D4_ + k]);
  float4 fv = ld4(&f_cum[((size_t)b*L_ + i)*D4_ + k]);
  float4 bv = ld4(&b_cum[((size_t)b*L_ + j)*D4_ + k]);
  float4 rv = ld4(&pos_tab[(size_t)(i - j + 255)*D4_ + k]);
  float h0 = cv.x+pv.x+fv.x-bv.x+rv.x;
  float h1 = cv.y+pv.y+fv.y-bv.y+rv.y;
  float h2 = cv.z+pv.z+fv.z-bv.z+rv.z;
  float h3 = cv.w+pv.w+fv.w-bv.w+rv.w;
  float s = h0+h1+h2+h3;
  #pragma unroll
  for (int m=1;m<64;m<<=1) s += __shfl_xor(s, m);
  float mu = s * (1.f/D4_);
  float d0=h0-mu, d1=h1-mu, d2=h2-mu, d3=h3-mu;
  float ss = d0*d0+d1*d1+d2*d2+d3*d3;
  #pragma unroll
  for (int m=1;m<64;m<<=1) ss += __shfl_xor(ss, m);
  float rstd = rsqrtf(ss*(1.f/D4_) + 1e-5f);
  float4 g  = ld4(&ln_g[k]);
  float4 bt = ld4(&ln_b[k]);
  float v0 = tanhf(d0*rstd*g.x + bt.x);
  float v1 = tanhf(d1*rstd*g.y + bt.y);
  float v2 = tanhf(d2*rstd*g.z + bt.z);
  float v3 = tanhf(d3*rstd*g.w + bt.w);
  float part[8];
  #pragma unroll
  for (int r=0;r<8;r++){
    float4 w = ld4(&Wo[r*D4_ + k]);
    part[r] = v0*w.x + v1*w.y + v2*w.z + v3*w.w;
  }
  #pragma unroll
  for (int m=1;m<64;m<<=1){
    #pragma unroll
    for (int r=0;r<8;r++) part[r] += __shfl_xor(part[r], m);
  }
  if (lane == 0){
    int len = lengths[b];
    bool vis = (i < len) && (j < len);
    float o[8];
    #pragma unroll
    for (int r=0;r<8;r++){
      float sc = (part[r] + bo[r]) * (1.f/7.5f);
      o[r] = vis ? tanhf(sc)*7.5f : -64.f;
    }
    float* lp = out + (((size_t)b*L_ + i)*L_ + j)*R_;
    st4(lp,     make_float4(o[0],o[1],o[2],o[3]));
    st4(lp + 4, make_float4(o[4],o[5],o[6],o[7]));
    if (i == j){
      float* rp = out + (size_t)B_*L_*L_*R_ + ((size_t)b*L_ + i)*R_;
      st4(rp,     make_float4(o[0],o[1],o[2],o[3]));
      st4(rp + 4, make_float4(o[4],o[5],o[6],o[7]));
    }
  }
}

// ---------------------------------------------------------------------------
extern "C" void kernel_launch(void* const* d_in, const int* in_sizes, int n_in,
                              void* d_out, int out_size, void* d_ws, size_t ws_size,
                              hipStream_t stream)
{
  const float* X      = (const float*)d_in[0];
  const float* conv_w = (const float*)d_in[1];
  const float* conv_b = (const float*)d_in[2];
  const float* Wc     = (const float*)d_in[3];
  const float* bc     = (const float*)d_in[4];
  const float* Wp     = (const float*)d_in[5];
  const float* bp     = (const float*)d_in[6];
  const float* Wcum   = (const float*)d_in[7];
  const float* bcum   = (const float*)d_in[8];
  const float* Wr     = (const float*)d_in[9];
  const float* br     = (const float*)d_in[10];
  const float* ln_g   = (const float*)d_in[11];
  const float* ln_b   = (const float*)d_in[12];
  const float* Wo     = (const float*)d_in[13];
  const float* bo     = (const float*)d_in[14];
  const unsigned char* mask = (const unsigned char*)d_in[15];
  float* out = (float*)d_out;

  char* base = (char*)d_ws;
  auto alloc = [&](size_t bytes){ char* p = base; base += (bytes + 255) & ~(size_t)255; return p; };
  int*    lengths = (int*)   alloc(64);
  __bf16* Xb_u    = (__bf16*)alloc(2097152);
  __bf16* Xb_m    = (__bf16*)alloc(2097152);
  __bf16* Wbc     = (__bf16*)alloc(18874368);
  __bf16* Wcum_b  = (__bf16*)alloc(524288);
  __bf16* Wc_b    = (__bf16*)alloc(524288);
  __bf16* Wp_b    = (__bf16*)alloc(524288);
  __bf16* Wr_b    = (__bf16*)alloc(524288);
  __bf16* pe_b    = (__bf16*)alloc(1046528);
  float*  ybuf    = (float*) alloc(4194304);
  __bf16* hb_mid  = (__bf16*)alloc(2097152);
  __bf16* hb_fin  = (__bf16*)alloc(2097152);
  float*  cum     = (float*) alloc(1048576);
  float*  f_cum   = (float*) alloc(1048576);
  float*  b_cum   = (float*) alloc(1048576);
  float*  c_lin   = (float*) alloc(1048576);
  float*  p_lin   = (float*) alloc(1048576);
  float*  pos_tab = (float*) alloc(523264);

  float* h_out = out + (size_t)B_*L_*L_*R_ + (size_t)B_*L_*R_;

  k_lengths<<<1, 64, 0, stream>>>(mask, lengths);
  k_prep_x<<<512, 256, 0, stream>>>(X, lengths, Xb_u, Xb_m);
  k_prep_convw<<<3072, 256, 0, stream>>>(conv_w, Wbc);
  k_prep_w<<<dim3(128,4), 256, 0, stream>>>(Wcum, Wc, Wp, Wr, Wcum_b, Wc_b, Wp_b, Wr_b);
  k_pe<<<511, 256, 0, stream>>>(pe_b);

  // cum = X @ Wcum^T + bcum ; cumsum
  k_gemm_mfma<<<dim3(16,4), 256, 0, stream>>>(Xb_u, Wcum_b, bcum, cum, B_*L_, D4_, D_);
  k_cumsum<<<B_, 256, 0, stream>>>(cum, lengths, f_cum, b_cum);

  // conv stack
  k_conv_mfma<<<dim3(16,16), 256, 0, stream>>>(Xb_m,   Wbc, conv_b, ybuf, 0);
  k_ln_tanh_mid<<<B_*L_, 256, 0, stream>>>(ybuf, lengths, hb_mid);
  k_conv_mfma<<<dim3(16,16), 256, 0, stream>>>(hb_mid, Wbc, conv_b, ybuf, 1);
  k_ln_tanh_mid<<<B_*L_, 256, 0, stream>>>(ybuf, lengths, hb_mid);
  k_conv_mfma<<<dim3(16,16), 256, 0, stream>>>(hb_mid, Wbc, conv_b, ybuf, 2);
  k_ln_tanh_fin<<<B_*L_, 256, 0, stream>>>(ybuf, h_out, hb_fin);

  // linears
  k_gemm_mfma<<<dim3(16,4), 256, 0, stream>>>(hb_fin, Wc_b, bc, c_lin, B_*L_, D4_, D_);
  k_gemm_mfma<<<dim3(16,4), 256, 0, stream>>>(hb_fin, Wp_b, bp, p_lin, B_*L_, D4_, D_);
  k_gemm_mfma<<<dim3(8,4),  256, 0, stream>>>(pe_b,   Wr_b, br, pos_tab, 511, D4_, D_);

  // pair kernel: logits + root
  k_pairs<<<(B_*L_*L_)/4, 256, 0, stream>>>(c_lin, p_lin, f_cum, b_cum, pos_tab,
                                            ln_g, ln_b, Wo, bo, lengths, out);
}

// Round 3
// 380.040 us; speedup vs baseline: 4.6021x; 1.5919x over previous
//
#include <hip/hip_runtime.h>

#define B_ 4
#define L_ 256
#define D_ 1024
#define D4_ 256
#define K_ 3
#define NL_ 3
#define MAXLEN_ 500
#define R_ 8

typedef __attribute__((ext_vector_type(8))) __bf16 bf16x8;
typedef __attribute__((ext_vector_type(4))) __bf16 bf16x4;
typedef __attribute__((ext_vector_type(4))) float f32x4;

__device__ __forceinline__ float4 ld4(const float* p){ return *reinterpret_cast<const float4*>(p); }
__device__ __forceinline__ void st4(float* p, float4 v){ *reinterpret_cast<float4*>(p) = v; }

// tanh via hardware exp2: ~6 VALU ops, abs err ~1e-7
__device__ __forceinline__ float fast_tanh(float x){
  x = fminf(fmaxf(x, -9.f), 9.f);
  float e = exp2f(x * 2.885390081777927f);     // e^{2x}
  return (e - 1.f) * __builtin_amdgcn_rcpf(e + 1.f);
}

// ---------------------------------------------------------------------------
// Mask decode (prefix mask): sniff dtype, count truths.
// ---------------------------------------------------------------------------
__global__ void k_lengths(const unsigned char* mask, int* lengths){
  int t = threadIdx.x;
  if (t >= B_) return;
  const unsigned int* w = (const unsigned int*)mask;
  unsigned int w0 = w[0];
  int stride = 1;
  if      (w0 == 0x01010101u) stride = 1;
  else if (w0 == 0x3F803F80u) stride = 2;
  else if (w0 == 0x3C003C00u) stride = 2;
  else if (w0 == 0x3F800000u) stride = 4;
  else if (w0 == 1u && w[1] == 1u) stride = 4;
  else if (w0 == 1u && w[1] == 0u) stride = 8;
  else if (w0 == 0u && w[1] == 0x3FF00000u) stride = 8;
  int c = 0;
  for (int l = 0; l < L_; l++){
    const unsigned char* e = mask + (size_t)(t*L_ + l)*stride;
    unsigned char nz = 0;
    for (int s = 0; s < stride; s++) nz |= e[s];
    c += (nz != 0) ? 1 : 0;
  }
  lengths[t] = c;
}

// ---------------------------------------------------------------------------
// PE rows used: t = i-j+255 in [0,510], position = 255 - t. Native trig.
// ---------------------------------------------------------------------------
__global__ void k_pe(__bf16* pe){
  int t = blockIdx.x;
  float posv = (float)(255 - t);
  const float c = -9.210340371976184f / (float)D_;
  for (int m = threadIdx.x; m < D_/2; m += blockDim.x){
    float div = __expf((float)(2*m) * c);
    float val = posv * div;
    pe[((size_t)t<<10) + 2*m]     = (__bf16)__sinf(val);
    pe[((size_t)t<<10) + 2*m + 1] = (__bf16)__cosf(val);
  }
}

// ---------------------------------------------------------------------------
// Prep: X f32 -> bf16 unmasked (cum GEMM) + masked (conv0 input)
// ---------------------------------------------------------------------------
__global__ void k_prep_x(const float* __restrict__ X, const int* __restrict__ lengths,
                         __bf16* __restrict__ xu, __bf16* __restrict__ xm){
  int idx = blockIdx.x*256 + threadIdx.x;
  int row = idx >> 7, c8 = (idx & 127) << 3;
  int b = row >> 8, l = row & 255;
  bool keep = l < lengths[b];
  const float* src = X + ((size_t)row << 10) + c8;
  bf16x8 u, m;
  #pragma unroll
  for (int e = 0; e < 8; e++){
    float f = src[e];
    u[e] = (__bf16)f;
    m[e] = keep ? (__bf16)f : (__bf16)0.f;
  }
  *reinterpret_cast<bf16x8*>(xu + ((size_t)row<<10) + c8) = u;
  *reinterpret_cast<bf16x8*>(xm + ((size_t)row<<10) + c8) = m;
}

// ---------------------------------------------------------------------------
// Prep: conv_w [L][O][C][T] f32 -> Wbc [L][T][O][C] bf16 (t-major)
// ---------------------------------------------------------------------------
__global__ void k_prep_convw(const float* __restrict__ cw, __bf16* __restrict__ wbc){
  int idx = blockIdx.x*256 + threadIdx.x;
  int layer = idx / 262144;
  int rem = idx & 262143;
  int o = rem >> 8, c4 = (rem & 255) << 2;
  const float* src = cw + (((size_t)layer*1024 + o)*1024 + c4)*3;
  float4 f0 = ld4(src), f1 = ld4(src+4), f2 = ld4(src+8);
  float tv[3][4] = {
    {f0.x, f0.w, f1.z, f2.y},
    {f0.y, f1.x, f1.w, f2.z},
    {f0.z, f1.y, f2.x, f2.w}
  };
  #pragma unroll
  for (int t = 0; t < 3; t++){
    bf16x4 v;
    #pragma unroll
    for (int e = 0; e < 4; e++) v[e] = (__bf16)tv[t][e];
    *reinterpret_cast<bf16x4*>(wbc + ((size_t)(layer*3+t)*1024 + o)*1024 + c4) = v;
  }
}

// ---------------------------------------------------------------------------
// Prep: 4 linear weights [256][1024] f32 -> bf16 (Wc_b,Wp_b contiguous -> N=512)
// ---------------------------------------------------------------------------
__global__ void k_prep_w(const float* __restrict__ w0, const float* __restrict__ w1,
                         const float* __restrict__ w2, const float* __restrict__ w3,
                         __bf16* __restrict__ o0, __bf16* __restrict__ o1,
                         __bf16* __restrict__ o2, __bf16* __restrict__ o3){
  const float* src; __bf16* dst;
  switch (blockIdx.y){
    case 0: src = w0; dst = o0; break;
    case 1: src = w1; dst = o1; break;
    case 2: src = w2; dst = o2; break;
    default: src = w3; dst = o3; break;
  }
  int idx = blockIdx.x*256 + threadIdx.x;
  const float* p = src + (size_t)idx*8;
  bf16x8 v;
  #pragma unroll
  for (int e = 0; e < 8; e++) v[e] = (__bf16)p[e];
  *reinterpret_cast<bf16x8*>(dst + (size_t)idx*8) = v;
}

// ---------------------------------------------------------------------------
// MFMA GEMM: C[M,N] = A @ B^T + bias (bias2 for cols>=256). 64x64 tile.
// ---------------------------------------------------------------------------
__global__ __launch_bounds__(256) void k_gemm_mfma(const __bf16* __restrict__ A,
                                                   const __bf16* __restrict__ Bw,
                                                   const float* __restrict__ bias,
                                                   const float* __restrict__ bias2,
                                                   float* __restrict__ C,
                                                   int M, int N, int Kd)
{
  __shared__ __align__(16) __bf16 As[64][64];
  __shared__ __align__(16) __bf16 Bs[64][64];
  int tid = threadIdx.x;
  int lane = tid & 63, wave = tid >> 6;
  int wm = (wave >> 1) << 5, wn = (wave & 1) << 5;
  int row0 = blockIdx.x << 6, col0 = blockIdx.y << 6;
  f32x4 acc[2][2] = {};
  for (int k0 = 0; k0 < Kd; k0 += 64){
    for (int idx = tid; idx < 512; idx += 256){
      int r = idx >> 3, c = idx & 7;
      int row = row0 + r;
      bf16x8 v = {};
      if (row < M) v = *reinterpret_cast<const bf16x8*>(A + (size_t)row*Kd + k0 + (c<<3));
      *reinterpret_cast<bf16x8*>(&As[r][(c ^ (r & 7)) << 3]) = v;
    }
    for (int idx = tid; idx < 512; idx += 256){
      int r = idx >> 3, c = idx & 7;
      bf16x8 v = *reinterpret_cast<const bf16x8*>(Bw + (size_t)(col0 + r)*Kd + k0 + (c<<3));
      *reinterpret_cast<bf16x8*>(&Bs[r][(c ^ (r & 7)) << 3]) = v;
    }
    __syncthreads();
    #pragma unroll
    for (int kk = 0; kk < 2; kk++){
      int kc = (kk << 2) + (lane >> 4);
      int ra0 = wm + (lane & 15), ra1 = ra0 + 16;
      int rb0 = wn + (lane & 15), rb1 = rb0 + 16;
      bf16x8 a0 = *reinterpret_cast<const bf16x8*>(&As[ra0][(kc ^ (ra0 & 7)) << 3]);
      bf16x8 a1 = *reinterpret_cast<const bf16x8*>(&As[ra1][(kc ^ (ra1 & 7)) << 3]);
      bf16x8 b0 = *reinterpret_cast<const bf16x8*>(&Bs[rb0][(kc ^ (rb0 & 7)) << 3]);
      bf16x8 b1 = *reinterpret_cast<const bf16x8*>(&Bs[rb1][(kc ^ (rb1 & 7)) << 3]);
      acc[0][0] = __builtin_amdgcn_mfma_f32_16x16x32_bf16(a0, b0, acc[0][0], 0, 0, 0);
      acc[0][1] = __builtin_amdgcn_mfma_f32_16x16x32_bf16(a0, b1, acc[0][1], 0, 0, 0);
      acc[1][0] = __builtin_amdgcn_mfma_f32_16x16x32_bf16(a1, b0, acc[1][0], 0, 0, 0);
      acc[1][1] = __builtin_amdgcn_mfma_f32_16x16x32_bf16(a1, b1, acc[1][1], 0, 0, 0);
    }
    __syncthreads();
  }
  #pragma unroll
  for (int mi = 0; mi < 2; mi++)
    #pragma unroll
    for (int ni = 0; ni < 2; ni++){
      int col = col0 + wn + (ni << 4) + (lane & 15);
      float bv = (col < 256) ? bias[col] : bias2[col - 256];
      #pragma unroll
      for (int e = 0; e < 4; e++){
        int row = row0 + wm + (mi << 4) + ((lane >> 4) << 2) + e;
        if (row < M) C[(size_t)row*N + col] = acc[mi][ni][e] + bv;
      }
    }
}

// ---------------------------------------------------------------------------
// Conv layer, K-split over blockIdx.z (2 halves of 512 channels). No bias;
// partials summed in LN kernels. y stride between z-parts = 1048576 floats.
// ---------------------------------------------------------------------------
__global__ __launch_bounds__(256) void k_conv_mfma(const __bf16* __restrict__ hb,
                                                   const __bf16* __restrict__ wbc,
                                                   float* __restrict__ y, int layer)
{
  __shared__ __align__(16) __bf16 As[66][64];
  __shared__ __align__(16) __bf16 Bs[3][64][64];
  int tid = threadIdx.x;
  int lane = tid & 63, wave = tid >> 6;
  int wm = (wave >> 1) << 5, wn = (wave & 1) << 5;
  int bx = blockIdx.x;
  int b = bx >> 2, l0 = (bx & 3) << 6;
  int o0 = blockIdx.y << 6;
  int z = blockIdx.z;
  f32x4 acc[2][2] = {};
  for (int ci = 0; ci < 8; ci++){
    int c0 = (z << 9) + (ci << 6);
    for (int idx = tid; idx < 528; idx += 256){
      int r = idx >> 3, c = idx & 7;
      int l = l0 - 1 + r;
      bf16x8 v = {};
      if (l >= 0 && l < L_)
        v = *reinterpret_cast<const bf16x8*>(hb + (((size_t)(b<<8) + l) << 10) + c0 + (c<<3));
      *reinterpret_cast<bf16x8*>(&As[r][(c ^ (r & 7)) << 3]) = v;
    }
    for (int idx = tid; idx < 1536; idx += 256){
      int t = idx >> 9, r = (idx >> 3) & 63, c = idx & 7;
      bf16x8 v = *reinterpret_cast<const bf16x8*>(
          wbc + ((size_t)((layer*3 + t) << 10) + o0 + r)*1024 + c0 + (c<<3));
      *reinterpret_cast<bf16x8*>(&Bs[t][r][(c ^ (r & 7)) << 3]) = v;
    }
    __syncthreads();
    #pragma unroll
    for (int t = 0; t < 3; t++){
      #pragma unroll
      for (int kk = 0; kk < 2; kk++){
        int kc = (kk << 2) + (lane >> 4);
        int ra0 = wm + (lane & 15) + t, ra1 = ra0 + 16;
        int rb0 = wn + (lane & 15),     rb1 = rb0 + 16;
        bf16x8 a0 = *reinterpret_cast<const bf16x8*>(&As[ra0][(kc ^ (ra0 & 7)) << 3]);
        bf16x8 a1 = *reinterpret_cast<const bf16x8*>(&As[ra1][(kc ^ (ra1 & 7)) << 3]);
        bf16x8 b0 = *reinterpret_cast<const bf16x8*>(&Bs[t][rb0][(kc ^ (rb0 & 7)) << 3]);
        bf16x8 b1 = *reinterpret_cast<const bf16x8*>(&Bs[t][rb1][(kc ^ (rb1 & 7)) << 3]);
        acc[0][0] = __builtin_amdgcn_mfma_f32_16x16x32_bf16(a0, b0, acc[0][0], 0, 0, 0);
        acc[0][1] = __builtin_amdgcn_mfma_f32_16x16x32_bf16(a0, b1, acc[0][1], 0, 0, 0);
        acc[1][0] = __builtin_amdgcn_mfma_f32_16x16x32_bf16(a1, b0, acc[1][0], 0, 0, 0);
        acc[1][1] = __builtin_amdgcn_mfma_f32_16x16x32_bf16(a1, b1, acc[1][1], 0, 0, 0);
      }
    }
    __syncthreads();
  }
  float* yz = y + (size_t)z * 1048576;
  #pragma unroll
  for (int mi = 0; mi < 2; mi++)
    #pragma unroll
    for (int ni = 0; ni < 2; ni++){
      int col = o0 + wn + (ni << 4) + (lane & 15);
      #pragma unroll
      for (int e = 0; e < 4; e++){
        int rowl = wm + (mi << 4) + ((lane >> 4) << 2) + e;
        yz[(((size_t)(b<<8) + l0 + rowl) << 10) + col] = acc[mi][ni][e];
      }
    }
}

// ---------------------------------------------------------------------------
// LN(1024)+tanh over (ypart0+ypart1+bias).
// ---------------------------------------------------------------------------
__device__ __forceinline__ void ln_core2(const float* y, const float* cb, int n, int tid,
                                         int lane, int wid, float* red,
                                         float4& v, float& mu, float& rstd){
  const float* yr = y + ((size_t)n << 10) + tid*4;
  float4 a0 = ld4(yr);
  float4 a1 = ld4(yr + 1048576);
  float4 bb = ld4(cb + tid*4);
  v = make_float4(a0.x+a1.x+bb.x, a0.y+a1.y+bb.y, a0.z+a1.z+bb.z, a0.w+a1.w+bb.w);
  float s = v.x+v.y+v.z+v.w;
  #pragma unroll
  for (int m=1;m<64;m<<=1) s += __shfl_xor(s, m);
  if (lane == 0) red[wid] = s;
  __syncthreads();
  mu = (red[0]+red[1]+red[2]+red[3]) * (1.f/D_);
  float d0=v.x-mu, d1=v.y-mu, d2=v.z-mu, d3=v.w-mu;
  float ss = d0*d0+d1*d1+d2*d2+d3*d3;
  #pragma unroll
  for (int m=1;m<64;m<<=1) ss += __shfl_xor(ss, m);
  if (lane == 0) red[8+wid] = ss;
  __syncthreads();
  rstd = rsqrtf((red[8]+red[9]+red[10]+red[11]) * (1.f/D_) + 1e-5f);
}

__global__ __launch_bounds__(256) void k_ln_tanh_mid(const float* __restrict__ y,
                                                     const float* __restrict__ cb,
                                                     const int* __restrict__ lengths,
                                                     __bf16* __restrict__ hb)
{
  __shared__ float red[16];
  int n = blockIdx.x;
  int tid = threadIdx.x, lane = tid & 63, wid = tid >> 6;
  float4 v; float mu, rstd;
  ln_core2(y, cb, n, tid, lane, wid, red, v, mu, rstd);
  int l = n & 255, b = n >> 8;
  float keep = (l < lengths[b]) ? 1.f : 0.f;
  bf16x4 o;
  o[0] = (__bf16)(fast_tanh((v.x-mu)*rstd) * keep);
  o[1] = (__bf16)(fast_tanh((v.y-mu)*rstd) * keep);
  o[2] = (__bf16)(fast_tanh((v.z-mu)*rstd) * keep);
  o[3] = (__bf16)(fast_tanh((v.w-mu)*rstd) * keep);
  *reinterpret_cast<bf16x4*>(hb + ((size_t)n<<10) + tid*4) = o;
}

__global__ __launch_bounds__(256) void k_ln_tanh_fin(const float* __restrict__ y,
                                                     const float* __restrict__ cb,
                                                     float* __restrict__ hf,
                                                     __bf16* __restrict__ hb)
{
  __shared__ float red[16];
  int n = blockIdx.x;
  int tid = threadIdx.x, lane = tid & 63, wid = tid >> 6;
  float4 v; float mu, rstd;
  ln_core2(y, cb, n, tid, lane, wid, red, v, mu, rstd);
  float t0 = fast_tanh((v.x-mu)*rstd), t1 = fast_tanh((v.y-mu)*rstd);
  float t2 = fast_tanh((v.z-mu)*rstd), t3 = fast_tanh((v.w-mu)*rstd);
  st4(&hf[((size_t)n<<10) + tid*4], make_float4(t0,t1,t2,t3));
  bf16x4 o; o[0]=(__bf16)t0; o[1]=(__bf16)t1; o[2]=(__bf16)t2; o[3]=(__bf16)t3;
  *reinterpret_cast<bf16x4*>(hb + ((size_t)n<<10) + tid*4) = o;
}

// ---------------------------------------------------------------------------
// Combine: wave-parallel masked cumsum of cum + fold into ci = c_lin + f_cum,
// pj = p_lin - b_cum. One wave per (b,k) column. cp is [1024][512].
// ---------------------------------------------------------------------------
__global__ __launch_bounds__(256) void k_combine(const float* __restrict__ cum,
                                                 const float* __restrict__ cp,
                                                 const int* __restrict__ lengths,
                                                 float* __restrict__ ci,
                                                 float* __restrict__ pj)
{
  int w = blockIdx.x*4 + (threadIdx.x >> 6);   // 1024 waves: (b,k)
  int lane = threadIdx.x & 63;
  int b = w >> 8, k = w & 255;
  int len = lengths[b];
  int rowbase = b << 8;
  float v[4], p[4];
  float run = 0.f;
  #pragma unroll
  for (int e = 0; e < 4; e++){
    int l = lane*4 + e;
    float x = cum[(((size_t)rowbase + l) << 8) + k];
    v[e] = (l >= len) ? x : 0.f;
    run += v[e]; p[e] = run;
  }
  float t = run, s = run;
  #pragma unroll
  for (int off = 1; off < 64; off <<= 1){
    float u = __shfl_up(s, off);
    if (lane >= off) s += u;
  }
  float excl = s - t;
  float total = __shfl(s, 63);
  #pragma unroll
  for (int e = 0; e < 4; e++){
    int l = lane*4 + e;
    size_t row = rowbase + l;
    float f_ex = excl + p[e] - v[e];
    float b_in = total - (excl + p[e]);
    ci[(row << 8) + k] = cp[row*512 + k]       + f_ex;
    pj[(row << 8) + k] = cp[row*512 + 256 + k] - b_in;
  }
}

// ---------------------------------------------------------------------------
// Pair kernel: one wave per (b, i, 16 j's). Weights/gains hoisted to regs.
// ---------------------------------------------------------------------------
__device__ __forceinline__ float mg(float a, float b, bool sel, int d){
  float t0 = sel ? b : a;
  float t1 = sel ? a : b;
  return t0 + __shfl_xor(t1, d);
}

__global__ __launch_bounds__(256) void k_pairs(const float* __restrict__ ci,
                                               const float* __restrict__ pj,
                                               const float* __restrict__ pos_tab,
                                               const float* __restrict__ ln_g,
                                               const float* __restrict__ ln_b,
                                               const float* __restrict__ Wo,
                                               const float* __restrict__ bo,
                                               const int* __restrict__ lengths,
                                               float* __restrict__ out)
{
  int tid = threadIdx.x;
  int lane = tid & 63;
  int w = blockIdx.x*4 + (tid >> 6);           // 16384 waves
  int b = w >> 12;
  int i = (w >> 4) & 255;
  int j0 = (w & 15) << 4;
  int k = lane << 2;
  float4 g4 = ld4(&ln_g[k]);
  float4 b4 = ld4(&ln_b[k]);
  float4 wv[8];
  #pragma unroll
  for (int r = 0; r < 8; r++) wv[r] = ld4(&Wo[r*D4_ + k]);
  float bor = bo[lane & 7];
  int len = lengths[b];
  bool visi = i < len;
  float4 civ = ld4(&ci[((((size_t)b<<8) + i) << 8) + k]);
  bool s1 = lane & 1, s2 = lane & 2, s4 = lane & 4;
  float* outb = out + ((((size_t)b<<8) + i) << 8) * 8;
  float* rootb = out + (size_t)B_*L_*L_*R_ + (((size_t)b<<8) + i)*8;

  for (int jj = 0; jj < 16; jj++){
    int j = j0 + jj;
    float4 pv = ld4(&pj[((((size_t)b<<8) + j) << 8) + k]);
    float4 rv = ld4(&pos_tab[(size_t)(i - j + 255)*D4_ + k]);
    float h0 = civ.x + pv.x + rv.x;
    float h1 = civ.y + pv.y + rv.y;
    float h2 = civ.z + pv.z + rv.z;
    float h3 = civ.w + pv.w + rv.w;
    float s = h0+h1+h2+h3;
    #pragma unroll
    for (int m=1;m<64;m<<=1) s += __shfl_xor(s, m);
    float mu = s * (1.f/D4_);
    float d0=h0-mu, d1=h1-mu, d2=h2-mu, d3=h3-mu;
    float ss = d0*d0+d1*d1+d2*d2+d3*d3;
    #pragma unroll
    for (int m=1;m<64;m<<=1) ss += __shfl_xor(ss, m);
    float rstd = rsqrtf(ss*(1.f/D4_) + 1e-5f);
    float v0 = fast_tanh(fmaf(d0*rstd, g4.x, b4.x));
    float v1 = fast_tanh(fmaf(d1*rstd, g4.y, b4.y));
    float v2 = fast_tanh(fmaf(d2*rstd, g4.z, b4.z));
    float v3 = fast_tanh(fmaf(d3*rstd, g4.w, b4.w));
    float p0 = fmaf(v3, wv[0].w, fmaf(v2, wv[0].z, fmaf(v1, wv[0].y, v0*wv[0].x)));
    float p1 = fmaf(v3, wv[1].w, fmaf(v2, wv[1].z, fmaf(v1, wv[1].y, v0*wv[1].x)));
    float p2 = fmaf(v3, wv[2].w, fmaf(v2, wv[2].z, fmaf(v1, wv[2].y, v0*wv[2].x)));
    float p3 = fmaf(v3, wv[3].w, fmaf(v2, wv[3].z, fmaf(v1, wv[3].y, v0*wv[3].x)));
    float p4 = fmaf(v3, wv[4].w, fmaf(v2, wv[4].z, fmaf(v1, wv[4].y, v0*wv[4].x)));
    float p5 = fmaf(v3, wv[5].w, fmaf(v2, wv[5].z, fmaf(v1, wv[5].y, v0*wv[5].x)));
    float p6 = fmaf(v3, wv[6].w, fmaf(v2, wv[6].z, fmaf(v1, wv[6].y, v0*wv[6].x)));
    float p7 = fmaf(v3, wv[7].w, fmaf(v2, wv[7].z, fmaf(v1, wv[7].y, v0*wv[7].x)));
    // pairwise merge tree: 8 regs x 64 lanes -> 1 reg, r = lane&7
    float m0 = mg(p0, p1, s1, 1);
    float m1 = mg(p2, p3, s1, 1);
    float m2 = mg(p4, p5, s1, 1);
    float m3 = mg(p6, p7, s1, 1);
    float n0 = mg(m0, m1, s2, 2);
    float n1 = mg(m2, m3, s2, 2);
    float f  = mg(n0, n1, s4, 4);
    f += __shfl_xor(f, 8);
    f += __shfl_xor(f, 16);
    f += __shfl_xor(f, 32);
    bool vis = visi && (j < len);
    float sc = (f + bor) * (1.f/7.5f);
    float o = vis ? fast_tanh(sc)*7.5f : -64.f;
    if (lane < 8){
      outb[(size_t)j*8 + lane] = o;
      if (i == j) rootb[lane] = o;
    }
  }
}

// ---------------------------------------------------------------------------
extern "C" void kernel_launch(void* const* d_in, const int* in_sizes, int n_in,
                              void* d_out, int out_size, void* d_ws, size_t ws_size,
                              hipStream_t stream)
{
  const float* X      = (const float*)d_in[0];
  const float* conv_w = (const float*)d_in[1];
  const float* conv_b = (const float*)d_in[2];
  const float* Wc     = (const float*)d_in[3];
  const float* bc     = (const float*)d_in[4];
  const float* Wp     = (const float*)d_in[5];
  const float* bp     = (const float*)d_in[6];
  const float* Wcum   = (const float*)d_in[7];
  const float* bcum   = (const float*)d_in[8];
  const float* Wr     = (const float*)d_in[9];
  const float* br     = (const float*)d_in[10];
  const float* ln_g   = (const float*)d_in[11];
  const float* ln_b   = (const float*)d_in[12];
  const float* Wo     = (const float*)d_in[13];
  const float* bo     = (const float*)d_in[14];
  const unsigned char* mask = (const unsigned char*)d_in[15];
  float* out = (float*)d_out;

  char* base = (char*)d_ws;
  auto alloc = [&](size_t bytes){ char* p = base; base += (bytes + 255) & ~(size_t)255; return p; };
  int*    lengths = (int*)   alloc(64);
  __bf16* Xb_u    = (__bf16*)alloc(2097152);
  __bf16* Xb_m    = (__bf16*)alloc(2097152);
  __bf16* Wbc     = (__bf16*)alloc(18874368);
  __bf16* Wcum_b  = (__bf16*)alloc(524288);
  __bf16* Wc_b    = (__bf16*)alloc(524288);   // contiguous with Wp_b -> [512][1024]
  __bf16* Wp_b    = (__bf16*)alloc(524288);
  __bf16* Wr_b    = (__bf16*)alloc(524288);
  __bf16* pe_b    = (__bf16*)alloc(1046528);
  float*  ypart   = (float*) alloc(8388608);  // 2 x [1024][1024] f32
  __bf16* hb_mid  = (__bf16*)alloc(2097152);
  __bf16* hb_fin  = (__bf16*)alloc(2097152);
  float*  cum     = (float*) alloc(1048576);
  float*  cp_lin  = (float*) alloc(2097152);  // [1024][512]
  float*  ci_c    = (float*) alloc(1048576);
  float*  pj_c    = (float*) alloc(1048576);
  float*  pos_tab = (float*) alloc(523264);
  (void)Wp_b;

  float* h_out = out + (size_t)B_*L_*L_*R_ + (size_t)B_*L_*R_;

  k_lengths<<<1, 64, 0, stream>>>(mask, lengths);
  k_prep_x<<<512, 256, 0, stream>>>(X, lengths, Xb_u, Xb_m);
  k_prep_convw<<<3072, 256, 0, stream>>>(conv_w, Wbc);
  k_prep_w<<<dim3(128,4), 256, 0, stream>>>(Wcum, Wc, Wp, Wr, Wcum_b, Wc_b, Wp_b, Wr_b);
  k_pe<<<511, 256, 0, stream>>>(pe_b);

  // cum = X @ Wcum^T + bcum
  k_gemm_mfma<<<dim3(16,4), 256, 0, stream>>>(Xb_u, Wcum_b, bcum, bcum, cum, B_*L_, D4_, D_);

  // conv stack (K-split x2, bias folded into LN)
  k_conv_mfma<<<dim3(16,16,2), 256, 0, stream>>>(Xb_m,   Wbc, ypart, 0);
  k_ln_tanh_mid<<<B_*L_, 256, 0, stream>>>(ypart, conv_b,        lengths, hb_mid);
  k_conv_mfma<<<dim3(16,16,2), 256, 0, stream>>>(hb_mid, Wbc, ypart, 1);
  k_ln_tanh_mid<<<B_*L_, 256, 0, stream>>>(ypart, conv_b + 1024, lengths, hb_mid);
  k_conv_mfma<<<dim3(16,16,2), 256, 0, stream>>>(hb_mid, Wbc, ypart, 2);
  k_ln_tanh_fin<<<B_*L_, 256, 0, stream>>>(ypart, conv_b + 2048, h_out, hb_fin);

  // c_lin & p_lin fused (N=512), pos
  k_gemm_mfma<<<dim3(16,8), 256, 0, stream>>>(hb_fin, Wc_b, bc, bp, cp_lin, B_*L_, 512, D_);
  k_gemm_mfma<<<dim3(8,4),  256, 0, stream>>>(pe_b,   Wr_b, br, br, pos_tab, 511, D4_, D_);

  // cumsum + fold
  k_combine<<<256, 256, 0, stream>>>(cum, cp_lin, lengths, ci_c, pj_c);

  // pairs
  k_pairs<<<4096, 256, 0, stream>>>(ci_c, pj_c, pos_tab, ln_g, ln_b, Wo, bo, lengths, out);
}

// Round 4
// 335.744 us; speedup vs baseline: 5.2093x; 1.1319x over previous
//
#include <hip/hip_runtime.h>

#define B_ 4
#define L_ 256
#define D_ 1024
#define D4_ 256
#define R_ 8

typedef __attribute__((ext_vector_type(8))) __bf16 bf16x8;
typedef __attribute__((ext_vector_type(4))) __bf16 bf16x4;
typedef __attribute__((ext_vector_type(4))) float f32x4;

__device__ __forceinline__ float4 ld4(const float* p){ return *reinterpret_cast<const float4*>(p); }
__device__ __forceinline__ void st4(float* p, float4 v){ *reinterpret_cast<float4*>(p) = v; }

// tanh via hardware exp2: ~8 VALU ops, abs err ~1e-7
__device__ __forceinline__ float fast_tanh(float x){
  x = fminf(fmaxf(x, -9.f), 9.f);
  float e = exp2f(x * 2.885390081777927f);     // e^{2x}
  return (e - 1.f) * __builtin_amdgcn_rcpf(e + 1.f);
}

// ---------------------------------------------------------------------------
// Mask decode (prefix mask): sniff dtype, count truths.
// ---------------------------------------------------------------------------
__global__ void k_lengths(const unsigned char* mask, int* lengths){
  int t = threadIdx.x;
  if (t >= B_) return;
  const unsigned int* w = (const unsigned int*)mask;
  unsigned int w0 = w[0];
  int stride = 1;
  if      (w0 == 0x01010101u) stride = 1;
  else if (w0 == 0x3F803F80u) stride = 2;
  else if (w0 == 0x3C003C00u) stride = 2;
  else if (w0 == 0x3F800000u) stride = 4;
  else if (w0 == 1u && w[1] == 1u) stride = 4;
  else if (w0 == 1u && w[1] == 0u) stride = 8;
  else if (w0 == 0u && w[1] == 0x3FF00000u) stride = 8;
  int c = 0;
  for (int l = 0; l < L_; l++){
    const unsigned char* e = mask + (size_t)(t*L_ + l)*stride;
    unsigned char nz = 0;
    for (int s = 0; s < stride; s++) nz |= e[s];
    c += (nz != 0) ? 1 : 0;
  }
  lengths[t] = c;
}

// ---------------------------------------------------------------------------
// Mega-prep: blocks [0,512) prep_x | [512,1024) prep_w | [1024,4096) conv_w
// | [4096,4607) PE table.
// ---------------------------------------------------------------------------
__global__ __launch_bounds__(256) void k_megaprep(
    const float* __restrict__ X, const int* __restrict__ lengths,
    __bf16* __restrict__ xu, __bf16* __restrict__ xm,
    const float* __restrict__ cw, __bf16* __restrict__ wbc,
    const float* __restrict__ w0, const float* __restrict__ w1,
    const float* __restrict__ w2, const float* __restrict__ w3,
    __bf16* __restrict__ o0, __bf16* __restrict__ o1,
    __bf16* __restrict__ o2, __bf16* __restrict__ o3,
    __bf16* __restrict__ pe)
{
  int blk = blockIdx.x, tid = threadIdx.x;
  if (blk < 512){
    int idx = blk*256 + tid;
    int row = idx >> 7, c8 = (idx & 127) << 3;
    int b = row >> 8, l = row & 255;
    bool keep = l < lengths[b];
    const float* src = X + ((size_t)row << 10) + c8;
    bf16x8 u, m;
    #pragma unroll
    for (int e = 0; e < 8; e++){
      float f = src[e];
      u[e] = (__bf16)f;
      m[e] = keep ? (__bf16)f : (__bf16)0.f;
    }
    *reinterpret_cast<bf16x8*>(xu + ((size_t)row<<10) + c8) = u;
    *reinterpret_cast<bf16x8*>(xm + ((size_t)row<<10) + c8) = m;
  } else if (blk < 1024){
    int sub = blk - 512;
    const float* src; __bf16* dst;
    switch (sub >> 7){
      case 0: src = w0; dst = o0; break;
      case 1: src = w1; dst = o1; break;
      case 2: src = w2; dst = o2; break;
      default: src = w3; dst = o3; break;
    }
    int idx = (sub & 127)*256 + tid;
    const float* p = src + (size_t)idx*8;
    bf16x8 v;
    #pragma unroll
    for (int e = 0; e < 8; e++) v[e] = (__bf16)p[e];
    *reinterpret_cast<bf16x8*>(dst + (size_t)idx*8) = v;
  } else if (blk < 4096){
    int idx = (blk - 1024)*256 + tid;
    int layer = idx / 262144;
    int rem = idx & 262143;
    int o = rem >> 8, c4 = (rem & 255) << 2;
    const float* src = cw + (((size_t)layer*1024 + o)*1024 + c4)*3;
    float4 f0 = ld4(src), f1 = ld4(src+4), f2 = ld4(src+8);
    float tv[3][4] = {
      {f0.x, f0.w, f1.z, f2.y},
      {f0.y, f1.x, f1.w, f2.z},
      {f0.z, f1.y, f2.x, f2.w}
    };
    #pragma unroll
    for (int t = 0; t < 3; t++){
      bf16x4 v;
      #pragma unroll
      for (int e = 0; e < 4; e++) v[e] = (__bf16)tv[t][e];
      *reinterpret_cast<bf16x4*>(wbc + ((size_t)(layer*3+t)*1024 + o)*1024 + c4) = v;
    }
  } else {
    int t = blk - 4096;                      // 0..510
    float posv = (float)(255 - t);
    const float c = -9.210340371976184f / (float)D_;
    for (int m = tid; m < D_/2; m += 256){
      float div = __expf((float)(2*m) * c);
      float val = posv * div;
      pe[((size_t)t<<10) + 2*m]     = (__bf16)__sinf(val);
      pe[((size_t)t<<10) + 2*m + 1] = (__bf16)__cosf(val);
    }
  }
}

// ---------------------------------------------------------------------------
// MFMA GEMM: C[M,N] = A @ B^T + bias (bias2 for cols>=256). 64x64 tile.
// If Ct != nullptr, store transposed-packed instead: Ct[(col/4)*512 + row][col%4].
// ---------------------------------------------------------------------------
__global__ __launch_bounds__(256) void k_gemm_mfma(const __bf16* __restrict__ A,
                                                   const __bf16* __restrict__ Bw,
                                                   const float* __restrict__ bias,
                                                   const float* __restrict__ bias2,
                                                   float* __restrict__ C,
                                                   float* __restrict__ Ct,
                                                   int M, int N, int Kd)
{
  __shared__ __align__(16) __bf16 As[64][64];
  __shared__ __align__(16) __bf16 Bs[64][64];
  int tid = threadIdx.x;
  int lane = tid & 63, wave = tid >> 6;
  int wm = (wave >> 1) << 5, wn = (wave & 1) << 5;
  int row0 = blockIdx.x << 6, col0 = blockIdx.y << 6;
  f32x4 acc[2][2] = {};
  for (int k0 = 0; k0 < Kd; k0 += 64){
    for (int idx = tid; idx < 512; idx += 256){
      int r = idx >> 3, c = idx & 7;
      int row = row0 + r;
      bf16x8 v = {};
      if (row < M) v = *reinterpret_cast<const bf16x8*>(A + (size_t)row*Kd + k0 + (c<<3));
      *reinterpret_cast<bf16x8*>(&As[r][(c ^ (r & 7)) << 3]) = v;
    }
    for (int idx = tid; idx < 512; idx += 256){
      int r = idx >> 3, c = idx & 7;
      bf16x8 v = *reinterpret_cast<const bf16x8*>(Bw + (size_t)(col0 + r)*Kd + k0 + (c<<3));
      *reinterpret_cast<bf16x8*>(&Bs[r][(c ^ (r & 7)) << 3]) = v;
    }
    __syncthreads();
    #pragma unroll
    for (int kk = 0; kk < 2; kk++){
      int kc = (kk << 2) + (lane >> 4);
      int ra0 = wm + (lane & 15), ra1 = ra0 + 16;
      int rb0 = wn + (lane & 15), rb1 = rb0 + 16;
      bf16x8 a0 = *reinterpret_cast<const bf16x8*>(&As[ra0][(kc ^ (ra0 & 7)) << 3]);
      bf16x8 a1 = *reinterpret_cast<const bf16x8*>(&As[ra1][(kc ^ (ra1 & 7)) << 3]);
      bf16x8 b0 = *reinterpret_cast<const bf16x8*>(&Bs[rb0][(kc ^ (rb0 & 7)) << 3]);
      bf16x8 b1 = *reinterpret_cast<const bf16x8*>(&Bs[rb1][(kc ^ (rb1 & 7)) << 3]);
      acc[0][0] = __builtin_amdgcn_mfma_f32_16x16x32_bf16(a0, b0, acc[0][0], 0, 0, 0);
      acc[0][1] = __builtin_amdgcn_mfma_f32_16x16x32_bf16(a0, b1, acc[0][1], 0, 0, 0);
      acc[1][0] = __builtin_amdgcn_mfma_f32_16x16x32_bf16(a1, b0, acc[1][0], 0, 0, 0);
      acc[1][1] = __builtin_amdgcn_mfma_f32_16x16x32_bf16(a1, b1, acc[1][1], 0, 0, 0);
    }
    __syncthreads();
  }
  #pragma unroll
  for (int mi = 0; mi < 2; mi++)
    #pragma unroll
    for (int ni = 0; ni < 2; ni++){
      int col = col0 + wn + (ni << 4) + (lane & 15);
      float bv = (col < 256) ? bias[col] : bias2[col - 256];
      int rowb = row0 + wm + (mi << 4) + ((lane >> 4) << 2);
      if (Ct){
        float* dst = Ct + ((size_t)(col >> 2) << 11) + (col & 3);
        #pragma unroll
        for (int e = 0; e < 4; e++){
          int row = rowb + e;
          if (row < M) dst[row << 2] = acc[mi][ni][e] + bv;
        }
      } else {
        #pragma unroll
        for (int e = 0; e < 4; e++){
          int row = rowb + e;
          if (row < M) C[(size_t)row*N + col] = acc[mi][ni][e] + bv;
        }
      }
    }
}

// ---------------------------------------------------------------------------
// Conv layer, z-split x4 (256 channels each), XCD-contiguous block swizzle.
// 1D grid of 1024. Partials (no bias) to y + z*1M.
// ---------------------------------------------------------------------------
__global__ __launch_bounds__(256) void k_conv_mfma(const __bf16* __restrict__ hb,
                                                   const __bf16* __restrict__ wbc,
                                                   float* __restrict__ y, int layer)
{
  __shared__ __align__(16) __bf16 As[66][64];
  __shared__ __align__(16) __bf16 Bs[3][64][64];
  int tid = threadIdx.x;
  int lane = tid & 63, wave = tid >> 6;
  int wm = (wave >> 1) << 5, wn = (wave & 1) << 5;
  int n = blockIdx.x;
  int swz = (n & 7)*128 + (n >> 3);      // XCD k handles contiguous swz chunk
  int bx = swz & 15, oy = (swz >> 4) & 15, z = swz >> 8;
  int b = bx >> 2, l0 = (bx & 3) << 6;
  int o0 = oy << 6;
  f32x4 acc[2][2] = {};
  for (int cc = 0; cc < 4; cc++){
    int c0 = (z << 8) + (cc << 6);
    for (int idx = tid; idx < 528; idx += 256){
      int r = idx >> 3, c = idx & 7;
      int l = l0 - 1 + r;
      bf16x8 v = {};
      if (l >= 0 && l < L_)
        v = *reinterpret_cast<const bf16x8*>(hb + (((size_t)(b<<8) + l) << 10) + c0 + (c<<3));
      *reinterpret_cast<bf16x8*>(&As[r][(c ^ (r & 7)) << 3]) = v;
    }
    for (int idx = tid; idx < 1536; idx += 256){
      int t = idx >> 9, r = (idx >> 3) & 63, c = idx & 7;
      bf16x8 v = *reinterpret_cast<const bf16x8*>(
          wbc + ((size_t)((layer*3 + t) << 10) + o0 + r)*1024 + c0 + (c<<3));
      *reinterpret_cast<bf16x8*>(&Bs[t][r][(c ^ (r & 7)) << 3]) = v;
    }
    __syncthreads();
    #pragma unroll
    for (int t = 0; t < 3; t++){
      #pragma unroll
      for (int kk = 0; kk < 2; kk++){
        int kc = (kk << 2) + (lane >> 4);
        int ra0 = wm + (lane & 15) + t, ra1 = ra0 + 16;
        int rb0 = wn + (lane & 15),     rb1 = rb0 + 16;
        bf16x8 a0 = *reinterpret_cast<const bf16x8*>(&As[ra0][(kc ^ (ra0 & 7)) << 3]);
        bf16x8 a1 = *reinterpret_cast<const bf16x8*>(&As[ra1][(kc ^ (ra1 & 7)) << 3]);
        bf16x8 b0 = *reinterpret_cast<const bf16x8*>(&Bs[t][rb0][(kc ^ (rb0 & 7)) << 3]);
        bf16x8 b1 = *reinterpret_cast<const bf16x8*>(&Bs[t][rb1][(kc ^ (rb1 & 7)) << 3]);
        acc[0][0] = __builtin_amdgcn_mfma_f32_16x16x32_bf16(a0, b0, acc[0][0], 0, 0, 0);
        acc[0][1] = __builtin_amdgcn_mfma_f32_16x16x32_bf16(a0, b1, acc[0][1], 0, 0, 0);
        acc[1][0] = __builtin_amdgcn_mfma_f32_16x16x32_bf16(a1, b0, acc[1][0], 0, 0, 0);
        acc[1][1] = __builtin_amdgcn_mfma_f32_16x16x32_bf16(a1, b1, acc[1][1], 0, 0, 0);
      }
    }
    __syncthreads();
  }
  float* yz = y + (size_t)z * 1048576;
  #pragma unroll
  for (int mi = 0; mi < 2; mi++)
    #pragma unroll
    for (int ni = 0; ni < 2; ni++){
      int col = o0 + wn + (ni << 4) + (lane & 15);
      #pragma unroll
      for (int e = 0; e < 4; e++){
        int rowl = wm + (mi << 4) + ((lane >> 4) << 2) + e;
        yz[(((size_t)(b<<8) + l0 + rowl) << 10) + col] = acc[mi][ni][e];
      }
    }
}

// ---------------------------------------------------------------------------
// LN(1024)+tanh over sum of 4 partials + bias.
// ---------------------------------------------------------------------------
__device__ __forceinline__ void ln_core4(const float* y, const float* cb, int n, int tid,
                                         int lane, int wid, float* red,
                                         float4& v, float& mu, float& rstd){
  const float* yr = y + ((size_t)n << 10) + tid*4;
  float4 a0 = ld4(yr);
  float4 a1 = ld4(yr + 1048576);
  float4 a2 = ld4(yr + 2097152);
  float4 a3 = ld4(yr + 3145728);
  float4 bb = ld4(cb + tid*4);
  v = make_float4(a0.x+a1.x+a2.x+a3.x+bb.x, a0.y+a1.y+a2.y+a3.y+bb.y,
                  a0.z+a1.z+a2.z+a3.z+bb.z, a0.w+a1.w+a2.w+a3.w+bb.w);
  float s = v.x+v.y+v.z+v.w;
  #pragma unroll
  for (int m=1;m<64;m<<=1) s += __shfl_xor(s, m);
  if (lane == 0) red[wid] = s;
  __syncthreads();
  mu = (red[0]+red[1]+red[2]+red[3]) * (1.f/D_);
  float d0=v.x-mu, d1=v.y-mu, d2=v.z-mu, d3=v.w-mu;
  float ss = d0*d0+d1*d1+d2*d2+d3*d3;
  #pragma unroll
  for (int m=1;m<64;m<<=1) ss += __shfl_xor(ss, m);
  if (lane == 0) red[8+wid] = ss;
  __syncthreads();
  rstd = rsqrtf((red[8]+red[9]+red[10]+red[11]) * (1.f/D_) + 1e-5f);
}

__global__ __launch_bounds__(256) void k_ln_tanh_mid(const float* __restrict__ y,
                                                     const float* __restrict__ cb,
                                                     const int* __restrict__ lengths,
                                                     __bf16* __restrict__ hb)
{
  __shared__ float red[16];
  int n = blockIdx.x;
  int tid = threadIdx.x, lane = tid & 63, wid = tid >> 6;
  float4 v; float mu, rstd;
  ln_core4(y, cb, n, tid, lane, wid, red, v, mu, rstd);
  int l = n & 255, b = n >> 8;
  float keep = (l < lengths[b]) ? 1.f : 0.f;
  bf16x4 o;
  o[0] = (__bf16)(fast_tanh((v.x-mu)*rstd) * keep);
  o[1] = (__bf16)(fast_tanh((v.y-mu)*rstd) * keep);
  o[2] = (__bf16)(fast_tanh((v.z-mu)*rstd) * keep);
  o[3] = (__bf16)(fast_tanh((v.w-mu)*rstd) * keep);
  *reinterpret_cast<bf16x4*>(hb + ((size_t)n<<10) + tid*4) = o;
}

__global__ __launch_bounds__(256) void k_ln_tanh_fin(const float* __restrict__ y,
                                                     const float* __restrict__ cb,
                                                     float* __restrict__ hf,
                                                     __bf16* __restrict__ hb)
{
  __shared__ float red[16];
  int n = blockIdx.x;
  int tid = threadIdx.x, lane = tid & 63, wid = tid >> 6;
  float4 v; float mu, rstd;
  ln_core4(y, cb, n, tid, lane, wid, red, v, mu, rstd);
  float t0 = fast_tanh((v.x-mu)*rstd), t1 = fast_tanh((v.y-mu)*rstd);
  float t2 = fast_tanh((v.z-mu)*rstd), t3 = fast_tanh((v.w-mu)*rstd);
  st4(&hf[((size_t)n<<10) + tid*4], make_float4(t0,t1,t2,t3));
  bf16x4 o; o[0]=(__bf16)t0; o[1]=(__bf16)t1; o[2]=(__bf16)t2; o[3]=(__bf16)t3;
  *reinterpret_cast<bf16x4*>(hb + ((size_t)n<<10) + tid*4) = o;
}

// ---------------------------------------------------------------------------
// Combine: wave-parallel masked cumsum + fold. Writes ci row-major and
// pj transposed-packed: pjt[(k4*4+b)*256 + j][4] (k4 = k/4, element k%4).
// ---------------------------------------------------------------------------
__global__ __launch_bounds__(256) void k_combine(const float* __restrict__ cum,
                                                 const float* __restrict__ cp,
                                                 const int* __restrict__ lengths,
                                                 float* __restrict__ ci,
                                                 float* __restrict__ pjt)
{
  int w = blockIdx.x*4 + (threadIdx.x >> 6);   // 1024 waves: (b,k)
  int lane = threadIdx.x & 63;
  int b = w >> 8, k = w & 255;
  int len = lengths[b];
  int rowbase = b << 8;
  float v[4], p[4];
  float run = 0.f;
  #pragma unroll
  for (int e = 0; e < 4; e++){
    int l = lane*4 + e;
    float x = cum[(((size_t)rowbase + l) << 8) + k];
    v[e] = (l >= len) ? x : 0.f;
    run += v[e]; p[e] = run;
  }
  float t = run, s = run;
  #pragma unroll
  for (int off = 1; off < 64; off <<= 1){
    float u = __shfl_up(s, off);
    if (lane >= off) s += u;
  }
  float excl = s - t;
  float total = __shfl(s, 63);
  float* pjb = pjt + (((size_t)((k >> 2)*4 + b)) << 10) + (k & 3);
  #pragma unroll
  for (int e = 0; e < 4; e++){
    int l = lane*4 + e;
    size_t row = rowbase + l;
    float f_ex = excl + p[e] - v[e];
    float b_in = total - (excl + p[e]);
    ci[(row << 8) + k] = cp[row*512 + k] + f_ex;
    pjb[l << 2] = cp[row*512 + 256 + k] - b_in;
  }
}

// ---------------------------------------------------------------------------
// Pair kernel v3: block = (b,i), thread = j. Channels serial, no shuffles.
// Pass 1: thread-local mean/var. Pass 2: normalize+tanh+8-way projection.
// ---------------------------------------------------------------------------
__global__ __launch_bounds__(256) void k_pairs(const float* __restrict__ ci,
                                               const float* __restrict__ pjt,
                                               const float* __restrict__ post,
                                               const float* __restrict__ ln_g,
                                               const float* __restrict__ ln_b,
                                               const float* __restrict__ Wo,
                                               const float* __restrict__ bo,
                                               const int* __restrict__ lengths,
                                               float* __restrict__ out)
{
  __shared__ __align__(16) float lci[256];
  __shared__ __align__(16) float lg[256];
  __shared__ __align__(16) float lb[256];
  __shared__ __align__(16) float lwo[2048];
  int bi = blockIdx.x;
  int b = bi >> 8, i = bi & 255;
  int j = threadIdx.x;
  lci[j] = ci[((size_t)bi << 8) + j];
  lg[j] = ln_g[j];
  lb[j] = ln_b[j];
  for (int t = j; t < 2048; t += 256) lwo[t] = Wo[((t & 7) << 8) + (t >> 3)];
  __syncthreads();
  int len = lengths[b];
  int d = i - j + 255;
  const float* pjb = pjt + (((size_t)b) << 10) + (j << 2);   // + k4*4096
  const float* pob = post + ((size_t)d << 2);                // + k4*2048
  // pass 1: stats
  float s = 0.f, q = 0.f;
  #pragma unroll 8
  for (int k4 = 0; k4 < 64; k4++){
    float4 c4 = ld4(&lci[k4 << 2]);
    float4 pv = ld4(pjb + ((size_t)k4 << 12));
    float4 ov = ld4(pob + ((size_t)k4 << 11));
    float h0 = c4.x+pv.x+ov.x, h1 = c4.y+pv.y+ov.y;
    float h2 = c4.z+pv.z+ov.z, h3 = c4.w+pv.w+ov.w;
    s += h0+h1+h2+h3;
    q = fmaf(h0,h0,q); q = fmaf(h1,h1,q); q = fmaf(h2,h2,q); q = fmaf(h3,h3,q);
  }
  float mu = s * (1.f/256.f);
  float rstd = rsqrtf(fmaf(-mu, mu, q * (1.f/256.f)) + 1e-5f);
  // pass 2: normalize + tanh + project
  float a0=0,a1=0,a2=0,a3=0,a4=0,a5=0,a6=0,a7=0;
  #pragma unroll 4
  for (int k4 = 0; k4 < 64; k4++){
    float4 c4 = ld4(&lci[k4 << 2]);
    float4 pv = ld4(pjb + ((size_t)k4 << 12));
    float4 ov = ld4(pob + ((size_t)k4 << 11));
    float4 g4 = ld4(&lg[k4 << 2]);
    float4 b4 = ld4(&lb[k4 << 2]);
    float h[4] = {c4.x+pv.x+ov.x, c4.y+pv.y+ov.y, c4.z+pv.z+ov.z, c4.w+pv.w+ov.w};
    float gg[4] = {g4.x,g4.y,g4.z,g4.w};
    float bb[4] = {b4.x,b4.y,b4.z,b4.w};
    #pragma unroll
    for (int e = 0; e < 4; e++){
      float v = fast_tanh(fmaf((h[e]-mu)*rstd, gg[e], bb[e]));
      float4 w0 = ld4(&lwo[((k4<<2)+e)<<3]);
      float4 w1 = ld4(&lwo[(((k4<<2)+e)<<3)+4]);
      a0 = fmaf(v, w0.x, a0); a1 = fmaf(v, w0.y, a1);
      a2 = fmaf(v, w0.z, a2); a3 = fmaf(v, w0.w, a3);
      a4 = fmaf(v, w1.x, a4); a5 = fmaf(v, w1.y, a5);
      a6 = fmaf(v, w1.z, a6); a7 = fmaf(v, w1.w, a7);
    }
  }
  bool vis = (i < len) && (j < len);
  float acc[8] = {a0,a1,a2,a3,a4,a5,a6,a7};
  float res[8];
  #pragma unroll
  for (int r = 0; r < 8; r++){
    float sc = (acc[r] + bo[r]) * (1.f/7.5f);
    res[r] = vis ? fast_tanh(sc)*7.5f : -64.f;
  }
  float* lp = out + ((((size_t)bi) << 8) + j)*8;
  st4(lp,     make_float4(res[0],res[1],res[2],res[3]));
  st4(lp + 4, make_float4(res[4],res[5],res[6],res[7]));
  if (j == i){
    float* rp = out + (size_t)B_*L_*L_*R_ + ((size_t)bi)*8;
    st4(rp,     make_float4(res[0],res[1],res[2],res[3]));
    st4(rp + 4, make_float4(res[4],res[5],res[6],res[7]));
  }
}

// ---------------------------------------------------------------------------
extern "C" void kernel_launch(void* const* d_in, const int* in_sizes, int n_in,
                              void* d_out, int out_size, void* d_ws, size_t ws_size,
                              hipStream_t stream)
{
  const float* X      = (const float*)d_in[0];
  const float* conv_w = (const float*)d_in[1];
  const float* conv_b = (const float*)d_in[2];
  const float* Wc     = (const float*)d_in[3];
  const float* bc     = (const float*)d_in[4];
  const float* Wp     = (const float*)d_in[5];
  const float* bp     = (const float*)d_in[6];
  const float* Wcum   = (const float*)d_in[7];
  const float* bcum   = (const float*)d_in[8];
  const float* Wr     = (const float*)d_in[9];
  const float* br     = (const float*)d_in[10];
  const float* ln_g   = (const float*)d_in[11];
  const float* ln_b   = (const float*)d_in[12];
  const float* Wo     = (const float*)d_in[13];
  const float* bo     = (const float*)d_in[14];
  const unsigned char* mask = (const unsigned char*)d_in[15];
  float* out = (float*)d_out;

  char* base = (char*)d_ws;
  auto alloc = [&](size_t bytes){ char* p = base; base += (bytes + 255) & ~(size_t)255; return p; };
  int*    lengths = (int*)   alloc(64);
  __bf16* Xb_u    = (__bf16*)alloc(2097152);
  __bf16* Xb_m    = (__bf16*)alloc(2097152);
  __bf16* Wbc     = (__bf16*)alloc(18874368);
  __bf16* Wcum_b  = (__bf16*)alloc(524288);
  __bf16* Wc_b    = (__bf16*)alloc(524288);   // contiguous with Wp_b -> [512][1024]
  __bf16* Wp_b    = (__bf16*)alloc(524288);
  __bf16* Wr_b    = (__bf16*)alloc(524288);
  __bf16* pe_b    = (__bf16*)alloc(1046528);
  float*  ypart   = (float*) alloc(16777216); // 4 x [1024][1024] f32
  __bf16* hb_mid  = (__bf16*)alloc(2097152);
  __bf16* hb_fin  = (__bf16*)alloc(2097152);
  float*  cum     = (float*) alloc(1048576);
  float*  cp_lin  = (float*) alloc(2097152);  // [1024][512]
  float*  ci_c    = (float*) alloc(1048576);  // [b][i][256]
  float*  pj_t    = (float*) alloc(1048576);  // [k4][b][j][4]
  float*  pos_t   = (float*) alloc(524288);   // [k4][512 d][4]

  float* h_out = out + (size_t)B_*L_*L_*R_ + (size_t)B_*L_*R_;

  k_lengths<<<1, 64, 0, stream>>>(mask, lengths);
  k_megaprep<<<4607, 256, 0, stream>>>(X, lengths, Xb_u, Xb_m, conv_w, Wbc,
                                       Wcum, Wc, Wp, Wr, Wcum_b, Wc_b, Wp_b, Wr_b, pe_b);

  // cum = X @ Wcum^T + bcum
  k_gemm_mfma<<<dim3(16,4), 256, 0, stream>>>(Xb_u, Wcum_b, bcum, bcum, cum, nullptr,
                                              B_*L_, D4_, D_);

  // conv stack (z-split x4, XCD swizzle, bias folded into LN)
  k_conv_mfma<<<1024, 256, 0, stream>>>(Xb_m,   Wbc, ypart, 0);
  k_ln_tanh_mid<<<B_*L_, 256, 0, stream>>>(ypart, conv_b,        lengths, hb_mid);
  k_conv_mfma<<<1024, 256, 0, stream>>>(hb_mid, Wbc, ypart, 1);
  k_ln_tanh_mid<<<B_*L_, 256, 0, stream>>>(ypart, conv_b + 1024, lengths, hb_mid);
  k_conv_mfma<<<1024, 256, 0, stream>>>(hb_mid, Wbc, ypart, 2);
  k_ln_tanh_fin<<<B_*L_, 256, 0, stream>>>(ypart, conv_b + 2048, h_out, hb_fin);

  // c_lin & p_lin fused (N=512); pos GEMM -> transposed-packed pos_t
  k_gemm_mfma<<<dim3(16,8), 256, 0, stream>>>(hb_fin, Wc_b, bc, bp, cp_lin, nullptr,
                                              B_*L_, 512, D_);
  k_gemm_mfma<<<dim3(8,4),  256, 0, stream>>>(pe_b, Wr_b, br, br, nullptr, pos_t,
                                              511, D4_, D_);

  // cumsum + fold (writes ci row-major, pj transposed-packed)
  k_combine<<<256, 256, 0, stream>>>(cum, cp_lin, lengths, ci_c, pj_t);

  // pairs
  k_pairs<<<B_*L_, 256, 0, stream>>>(ci_c, pj_t, pos_t, ln_g, ln_b, Wo, bo, lengths, out);
}

// Round 6
// 262.769 us; speedup vs baseline: 6.6560x; 1.2777x over previous
//
#include <hip/hip_runtime.h>

#define B_ 4
#define L_ 256
#define D_ 1024
#define D4_ 256
#define R_ 8

typedef __attribute__((ext_vector_type(8))) __bf16 bf16x8;
typedef __attribute__((ext_vector_type(4))) __bf16 bf16x4;
typedef __attribute__((ext_vector_type(4))) float f32x4;

__device__ __forceinline__ float4 ld4(const float* p){ return *reinterpret_cast<const float4*>(p); }
__device__ __forceinline__ void st4(float* p, float4 v){ *reinterpret_cast<float4*>(p) = v; }

// tanh via hardware exp2: ~8 VALU ops, abs err ~1e-7
__device__ __forceinline__ float fast_tanh(float x){
  x = fminf(fmaxf(x, -9.f), 9.f);
  float e = exp2f(x * 2.885390081777927f);     // e^{2x}
  return (e - 1.f) * __builtin_amdgcn_rcpf(e + 1.f);
}

// ---------------------------------------------------------------------------
// Mask decode, parallel: wave per b, lane covers 4 positions.
// ---------------------------------------------------------------------------
__global__ void k_lengths(const unsigned char* mask, int* lengths){
  int tid = threadIdx.x;
  int b = tid >> 6, lane = tid & 63;
  const unsigned int* w = (const unsigned int*)mask;
  unsigned int w0 = w[0];
  int stride = 1;
  if      (w0 == 0x01010101u) stride = 1;
  else if (w0 == 0x3F803F80u) stride = 2;
  else if (w0 == 0x3C003C00u) stride = 2;
  else if (w0 == 0x3F800000u) stride = 4;
  else if (w0 == 1u && w[1] == 1u) stride = 4;
  else if (w0 == 1u && w[1] == 0u) stride = 8;
  else if (w0 == 0u && w[1] == 0x3FF00000u) stride = 8;
  int c = 0;
  #pragma unroll
  for (int e = 0; e < 4; e++){
    int l = lane*4 + e;
    const unsigned char* p = mask + (size_t)(b*L_ + l)*stride;
    unsigned char nz = 0;
    for (int s = 0; s < stride; s++) nz |= p[s];
    c += (nz != 0) ? 1 : 0;
  }
  #pragma unroll
  for (int m = 1; m < 64; m <<= 1) c += __shfl_xor(c, m);
  if (lane == 0) lengths[b] = c;
}

// ---------------------------------------------------------------------------
// Mega-prep: [0,512) X->bf16 | [512,1024) linear weights | [1024,4096) conv_w
// | [4096,4607) PE table.
// ---------------------------------------------------------------------------
__global__ __launch_bounds__(256) void k_megaprep(
    const float* __restrict__ X, const int* __restrict__ lengths,
    __bf16* __restrict__ xu, __bf16* __restrict__ xm,
    const float* __restrict__ cw, __bf16* __restrict__ wbc,
    const float* __restrict__ w0, const float* __restrict__ w1,
    const float* __restrict__ w2, const float* __restrict__ w3,
    __bf16* __restrict__ o0, __bf16* __restrict__ o1,
    __bf16* __restrict__ o2, __bf16* __restrict__ o3,
    __bf16* __restrict__ pe)
{
  int blk = blockIdx.x, tid = threadIdx.x;
  if (blk < 512){
    int idx = blk*256 + tid;
    int row = idx >> 7, c8 = (idx & 127) << 3;
    int b = row >> 8, l = row & 255;
    bool keep = l < lengths[b];
    const float* src = X + ((size_t)row << 10) + c8;
    bf16x8 u, m;
    #pragma unroll
    for (int e = 0; e < 8; e++){
      float f = src[e];
      u[e] = (__bf16)f;
      m[e] = keep ? (__bf16)f : (__bf16)0.f;
    }
    *reinterpret_cast<bf16x8*>(xu + ((size_t)row<<10) + c8) = u;
    *reinterpret_cast<bf16x8*>(xm + ((size_t)row<<10) + c8) = m;
  } else if (blk < 1024){
    int sub = blk - 512;
    const float* src; __bf16* dst;
    switch (sub >> 7){
      case 0: src = w0; dst = o0; break;
      case 1: src = w1; dst = o1; break;
      case 2: src = w2; dst = o2; break;
      default: src = w3; dst = o3; break;
    }
    int idx = (sub & 127)*256 + tid;
    const float* p = src + (size_t)idx*8;
    bf16x8 v;
    #pragma unroll
    for (int e = 0; e < 8; e++) v[e] = (__bf16)p[e];
    *reinterpret_cast<bf16x8*>(dst + (size_t)idx*8) = v;
  } else if (blk < 4096){
    int idx = (blk - 1024)*256 + tid;
    int layer = idx / 262144;
    int rem = idx & 262143;
    int o = rem >> 8, c4 = (rem & 255) << 2;
    const float* src = cw + (((size_t)layer*1024 + o)*1024 + c4)*3;
    float4 f0 = ld4(src), f1 = ld4(src+4), f2 = ld4(src+8);
    float tv[3][4] = {
      {f0.x, f0.w, f1.z, f2.y},
      {f0.y, f1.x, f1.w, f2.z},
      {f0.z, f1.y, f2.x, f2.w}
    };
    #pragma unroll
    for (int t = 0; t < 3; t++){
      bf16x4 v;
      #pragma unroll
      for (int e = 0; e < 4; e++) v[e] = (__bf16)tv[t][e];
      *reinterpret_cast<bf16x4*>(wbc + ((size_t)(layer*3+t)*1024 + o)*1024 + c4) = v;
    }
  } else {
    int t = blk - 4096;
    float posv = (float)(255 - t);
    const float c = -9.210340371976184f / (float)D_;
    for (int m = tid; m < D_/2; m += 256){
      float div = __expf((float)(2*m) * c);
      float val = posv * div;
      pe[((size_t)t<<10) + 2*m]     = (__bf16)__sinf(val);
      pe[((size_t)t<<10) + 2*m + 1] = (__bf16)__cosf(val);
    }
  }
}

// ---------------------------------------------------------------------------
// MFMA GEMM (64x64 tile). Ct: optional transposed-packed store.
// ---------------------------------------------------------------------------
__global__ __launch_bounds__(256) void k_gemm_mfma(const __bf16* __restrict__ A,
                                                   const __bf16* __restrict__ Bw,
                                                   const float* __restrict__ bias,
                                                   const float* __restrict__ bias2,
                                                   float* __restrict__ C,
                                                   float* __restrict__ Ct,
                                                   int M, int N, int Kd)
{
  __shared__ __align__(16) __bf16 As[64][64];
  __shared__ __align__(16) __bf16 Bs[64][64];
  int tid = threadIdx.x;
  int lane = tid & 63, wave = tid >> 6;
  int wm = (wave >> 1) << 5, wn = (wave & 1) << 5;
  int row0 = blockIdx.x << 6, col0 = blockIdx.y << 6;
  f32x4 acc[2][2] = {};
  for (int k0 = 0; k0 < Kd; k0 += 64){
    for (int idx = tid; idx < 512; idx += 256){
      int r = idx >> 3, c = idx & 7;
      int row = row0 + r;
      bf16x8 v = {};
      if (row < M) v = *reinterpret_cast<const bf16x8*>(A + (size_t)row*Kd + k0 + (c<<3));
      *reinterpret_cast<bf16x8*>(&As[r][(c ^ (r & 7)) << 3]) = v;
    }
    for (int idx = tid; idx < 512; idx += 256){
      int r = idx >> 3, c = idx & 7;
      bf16x8 v = *reinterpret_cast<const bf16x8*>(Bw + (size_t)(col0 + r)*Kd + k0 + (c<<3));
      *reinterpret_cast<bf16x8*>(&Bs[r][(c ^ (r & 7)) << 3]) = v;
    }
    __syncthreads();
    #pragma unroll
    for (int kk = 0; kk < 2; kk++){
      int kc = (kk << 2) + (lane >> 4);
      int ra0 = wm + (lane & 15), ra1 = ra0 + 16;
      int rb0 = wn + (lane & 15), rb1 = rb0 + 16;
      bf16x8 a0 = *reinterpret_cast<const bf16x8*>(&As[ra0][(kc ^ (ra0 & 7)) << 3]);
      bf16x8 a1 = *reinterpret_cast<const bf16x8*>(&As[ra1][(kc ^ (ra1 & 7)) << 3]);
      bf16x8 b0 = *reinterpret_cast<const bf16x8*>(&Bs[rb0][(kc ^ (rb0 & 7)) << 3]);
      bf16x8 b1 = *reinterpret_cast<const bf16x8*>(&Bs[rb1][(kc ^ (rb1 & 7)) << 3]);
      acc[0][0] = __builtin_amdgcn_mfma_f32_16x16x32_bf16(a0, b0, acc[0][0], 0, 0, 0);
      acc[0][1] = __builtin_amdgcn_mfma_f32_16x16x32_bf16(a0, b1, acc[0][1], 0, 0, 0);
      acc[1][0] = __builtin_amdgcn_mfma_f32_16x16x32_bf16(a1, b0, acc[1][0], 0, 0, 0);
      acc[1][1] = __builtin_amdgcn_mfma_f32_16x16x32_bf16(a1, b1, acc[1][1], 0, 0, 0);
    }
    __syncthreads();
  }
  #pragma unroll
  for (int mi = 0; mi < 2; mi++)
    #pragma unroll
    for (int ni = 0; ni < 2; ni++){
      int col = col0 + wn + (ni << 4) + (lane & 15);
      float bv = (col < 256) ? bias[col] : bias2[col - 256];
      int rowb = row0 + wm + (mi << 4) + ((lane >> 4) << 2);
      if (Ct){
        float* dst = Ct + ((size_t)(col >> 2) << 11) + (col & 3);
        #pragma unroll
        for (int e = 0; e < 4; e++){
          int row = rowb + e;
          if (row < M) dst[row << 2] = acc[mi][ni][e] + bv;
        }
      } else {
        #pragma unroll
        for (int e = 0; e < 4; e++){
          int row = rowb + e;
          if (row < M) C[(size_t)row*N + col] = acc[mi][ni][e] + bv;
        }
      }
    }
}

// ---------------------------------------------------------------------------
// Conv layer, z-split x4 (256 channels each), XCD-contiguous block swizzle.
// (round-4 verified body: direct LDS staging)
// ---------------------------------------------------------------------------
__global__ __launch_bounds__(256) void k_conv_mfma(const __bf16* __restrict__ hb,
                                                   const __bf16* __restrict__ wbc,
                                                   float* __restrict__ y, int layer)
{
  __shared__ __align__(16) __bf16 As[66][64];
  __shared__ __align__(16) __bf16 Bs[3][64][64];
  int tid = threadIdx.x;
  int lane = tid & 63, wave = tid >> 6;
  int wm = (wave >> 1) << 5, wn = (wave & 1) << 5;
  int n = blockIdx.x;
  int swz = (n & 7)*128 + (n >> 3);      // XCD k handles contiguous swz chunk
  int bx = swz & 15, oy = (swz >> 4) & 15, z = swz >> 8;
  int b = bx >> 2, l0 = (bx & 3) << 6;
  int o0 = oy << 6;
  f32x4 acc[2][2] = {};
  for (int cc = 0; cc < 4; cc++){
    int c0 = (z << 8) + (cc << 6);
    for (int idx = tid; idx < 528; idx += 256){
      int r = idx >> 3, c = idx & 7;
      int l = l0 - 1 + r;
      bf16x8 v = {};
      if (l >= 0 && l < L_)
        v = *reinterpret_cast<const bf16x8*>(hb + (((size_t)(b<<8) + l) << 10) + c0 + (c<<3));
      *reinterpret_cast<bf16x8*>(&As[r][(c ^ (r & 7)) << 3]) = v;
    }
    for (int idx = tid; idx < 1536; idx += 256){
      int t = idx >> 9, r = (idx >> 3) & 63, c = idx & 7;
      bf16x8 v = *reinterpret_cast<const bf16x8*>(
          wbc + ((size_t)((layer*3 + t) << 10) + o0 + r)*1024 + c0 + (c<<3));
      *reinterpret_cast<bf16x8*>(&Bs[t][r][(c ^ (r & 7)) << 3]) = v;
    }
    __syncthreads();
    #pragma unroll
    for (int t = 0; t < 3; t++){
      #pragma unroll
      for (int kk = 0; kk < 2; kk++){
        int kc = (kk << 2) + (lane >> 4);
        int ra0 = wm + (lane & 15) + t, ra1 = ra0 + 16;
        int rb0 = wn + (lane & 15),     rb1 = rb0 + 16;
        bf16x8 a0 = *reinterpret_cast<const bf16x8*>(&As[ra0][(kc ^ (ra0 & 7)) << 3]);
        bf16x8 a1 = *reinterpret_cast<const bf16x8*>(&As[ra1][(kc ^ (ra1 & 7)) << 3]);
        bf16x8 b0 = *reinterpret_cast<const bf16x8*>(&Bs[t][rb0][(kc ^ (rb0 & 7)) << 3]);
        bf16x8 b1 = *reinterpret_cast<const bf16x8*>(&Bs[t][rb1][(kc ^ (rb1 & 7)) << 3]);
        acc[0][0] = __builtin_amdgcn_mfma_f32_16x16x32_bf16(a0, b0, acc[0][0], 0, 0, 0);
        acc[0][1] = __builtin_amdgcn_mfma_f32_16x16x32_bf16(a0, b1, acc[0][1], 0, 0, 0);
        acc[1][0] = __builtin_amdgcn_mfma_f32_16x16x32_bf16(a1, b0, acc[1][0], 0, 0, 0);
        acc[1][1] = __builtin_amdgcn_mfma_f32_16x16x32_bf16(a1, b1, acc[1][1], 0, 0, 0);
      }
    }
    __syncthreads();
  }
  float* yz = y + (size_t)z * 1048576;
  #pragma unroll
  for (int mi = 0; mi < 2; mi++)
    #pragma unroll
    for (int ni = 0; ni < 2; ni++){
      int col = o0 + wn + (ni << 4) + (lane & 15);
      #pragma unroll
      for (int e = 0; e < 4; e++){
        int rowl = wm + (mi << 4) + ((lane >> 4) << 2) + e;
        yz[(((size_t)(b<<8) + l0 + rowl) << 10) + col] = acc[mi][ni][e];
      }
    }
}

// ---------------------------------------------------------------------------
// LN(1024)+tanh over sum of 4 partials + bias.
// ---------------------------------------------------------------------------
__device__ __forceinline__ void ln_core4(const float* y, const float* cb, int n, int tid,
                                         int lane, int wid, float* red,
                                         float4& v, float& mu, float& rstd){
  const float* yr = y + ((size_t)n << 10) + tid*4;
  float4 a0 = ld4(yr);
  float4 a1 = ld4(yr + 1048576);
  float4 a2 = ld4(yr + 2097152);
  float4 a3 = ld4(yr + 3145728);
  float4 bb = ld4(cb + tid*4);
  v = make_float4(a0.x+a1.x+a2.x+a3.x+bb.x, a0.y+a1.y+a2.y+a3.y+bb.y,
                  a0.z+a1.z+a2.z+a3.z+bb.z, a0.w+a1.w+a2.w+a3.w+bb.w);
  float s = v.x+v.y+v.z+v.w;
  #pragma unroll
  for (int m=1;m<64;m<<=1) s += __shfl_xor(s, m);
  if (lane == 0) red[wid] = s;
  __syncthreads();
  mu = (red[0]+red[1]+red[2]+red[3]) * (1.f/D_);
  float d0=v.x-mu, d1=v.y-mu, d2=v.z-mu, d3=v.w-mu;
  float ss = d0*d0+d1*d1+d2*d2+d3*d3;
  #pragma unroll
  for (int m=1;m<64;m<<=1) ss += __shfl_xor(ss, m);
  if (lane == 0) red[8+wid] = ss;
  __syncthreads();
  rstd = rsqrtf((red[8]+red[9]+red[10]+red[11]) * (1.f/D_) + 1e-5f);
}

__global__ __launch_bounds__(256) void k_ln_tanh_mid(const float* __restrict__ y,
                                                     const float* __restrict__ cb,
                                                     const int* __restrict__ lengths,
                                                     __bf16* __restrict__ hb)
{
  __shared__ float red[16];
  int n = blockIdx.x;
  int tid = threadIdx.x, lane = tid & 63, wid = tid >> 6;
  float4 v; float mu, rstd;
  ln_core4(y, cb, n, tid, lane, wid, red, v, mu, rstd);
  int l = n & 255, b = n >> 8;
  float keep = (l < lengths[b]) ? 1.f : 0.f;
  bf16x4 o;
  o[0] = (__bf16)(fast_tanh((v.x-mu)*rstd) * keep);
  o[1] = (__bf16)(fast_tanh((v.y-mu)*rstd) * keep);
  o[2] = (__bf16)(fast_tanh((v.z-mu)*rstd) * keep);
  o[3] = (__bf16)(fast_tanh((v.w-mu)*rstd) * keep);
  *reinterpret_cast<bf16x4*>(hb + ((size_t)n<<10) + tid*4) = o;
}

__global__ __launch_bounds__(256) void k_ln_tanh_fin(const float* __restrict__ y,
                                                     const float* __restrict__ cb,
                                                     float* __restrict__ hf,
                                                     __bf16* __restrict__ hb)
{
  __shared__ float red[16];
  int n = blockIdx.x;
  int tid = threadIdx.x, lane = tid & 63, wid = tid >> 6;
  float4 v; float mu, rstd;
  ln_core4(y, cb, n, tid, lane, wid, red, v, mu, rstd);
  float t0 = fast_tanh((v.x-mu)*rstd), t1 = fast_tanh((v.y-mu)*rstd);
  float t2 = fast_tanh((v.z-mu)*rstd), t3 = fast_tanh((v.w-mu)*rstd);
  st4(&hf[((size_t)n<<10) + tid*4], make_float4(t0,t1,t2,t3));
  bf16x4 o; o[0]=(__bf16)t0; o[1]=(__bf16)t1; o[2]=(__bf16)t2; o[3]=(__bf16)t3;
  *reinterpret_cast<bf16x4*>(hb + ((size_t)n<<10) + tid*4) = o;
}

// ---------------------------------------------------------------------------
// Combine: masked cumsum + fold. ci row-major; pj transposed-packed
// pjt[k4][b][j][4].
// ---------------------------------------------------------------------------
__global__ __launch_bounds__(256) void k_combine(const float* __restrict__ cum,
                                                 const float* __restrict__ cp,
                                                 const int* __restrict__ lengths,
                                                 float* __restrict__ ci,
                                                 float* __restrict__ pjt)
{
  int w = blockIdx.x*4 + (threadIdx.x >> 6);
  int lane = threadIdx.x & 63;
  int b = w >> 8, k = w & 255;
  int len = lengths[b];
  int rowbase = b << 8;
  float v[4], p[4];
  float run = 0.f;
  #pragma unroll
  for (int e = 0; e < 4; e++){
    int l = lane*4 + e;
    float x = cum[(((size_t)rowbase + l) << 8) + k];
    v[e] = (l >= len) ? x : 0.f;
    run += v[e]; p[e] = run;
  }
  float t = run, s = run;
  #pragma unroll
  for (int off = 1; off < 64; off <<= 1){
    float u = __shfl_up(s, off);
    if (lane >= off) s += u;
  }
  float excl = s - t;
  float total = __shfl(s, 63);
  float* pjb = pjt + (((size_t)((k >> 2)*4 + b)) << 10) + (k & 3);
  #pragma unroll
  for (int e = 0; e < 4; e++){
    int l = lane*4 + e;
    size_t row = rowbase + l;
    float f_ex = excl + p[e] - v[e];
    float b_in = total - (excl + p[e]);
    ci[(row << 8) + k] = cp[row*512 + k] + f_ex;
    pjb[l << 2] = cp[row*512 + 256 + k] - b_in;
  }
}

// ---------------------------------------------------------------------------
// Pair kernel v5: 2 threads per pair (channel halves), plain scalar f32.
// Block = (b, i, j-half of 128). tid: jj = tid&127, q = tid>>7 (k half).
// ---------------------------------------------------------------------------
__global__ __launch_bounds__(256) void k_pairs(const float* __restrict__ ci,
                                               const float* __restrict__ pjt,
                                               const float* __restrict__ post,
                                               const float* __restrict__ ln_g,
                                               const float* __restrict__ ln_b,
                                               const float* __restrict__ Wo,
                                               const float* __restrict__ bo,
                                               const int* __restrict__ lengths,
                                               float* __restrict__ out)
{
  __shared__ __align__(16) float lci[256];
  __shared__ __align__(16) float lg[256];
  __shared__ __align__(16) float lb[256];
  __shared__ __align__(16) float lwo[2048];      // [k][8]
  __shared__ float sred[512];                    // s / q partials
  __shared__ float pacc[128][9];                 // q=1 projection partials (+pad)

  int bid = blockIdx.x;
  int hlf = bid & 1;
  int bi = bid >> 1;                 // b*256 + i
  int b = bi >> 8, i = bi & 255;
  int tid = threadIdx.x;
  int jj = tid & 127, q = tid >> 7;
  int j = (hlf << 7) + jj;

  lci[tid] = ci[((size_t)bi << 8) + tid];
  lg[tid] = ln_g[tid];
  lb[tid] = ln_b[tid];
  for (int t = tid; t < 2048; t += 256) lwo[t] = Wo[((t & 7) << 8) + (t >> 3)];
  __syncthreads();

  int len = lengths[b];
  int d = i - j + 255;
  const float* pjb = pjt + ((size_t)b << 10) + (j << 2);
  const float* pob = post + ((size_t)d << 2);
  int k40 = q << 5;                  // 32 k4-groups per half

  // pass 1: partial stats over this thread's 128 channels
  float s = 0.f, qq = 0.f;
  #pragma unroll 4
  for (int k4 = k40; k4 < k40 + 32; k4++){
    float4 c4 = ld4(&lci[k4 << 2]);
    float4 pv = ld4(pjb + ((size_t)k4 << 12));
    float4 ov = ld4(pob + ((size_t)k4 << 11));
    float h0 = c4.x+pv.x+ov.x, h1 = c4.y+pv.y+ov.y;
    float h2 = c4.z+pv.z+ov.z, h3 = c4.w+pv.w+ov.w;
    s += h0+h1+h2+h3;
    qq = fmaf(h0,h0,qq); qq = fmaf(h1,h1,qq); qq = fmaf(h2,h2,qq); qq = fmaf(h3,h3,qq);
  }
  sred[tid] = s;
  sred[256 + tid] = qq;
  __syncthreads();
  float st = s + sred[tid ^ 128];
  float qt = qq + sred[256 + (tid ^ 128)];
  float mu = st * (1.f/256.f);
  float rstd = rsqrtf(fmaf(-mu, mu, qt * (1.f/256.f)) + 1e-5f);

  // pass 2: normalize + tanh + projection over this half
  float a0=0,a1=0,a2=0,a3=0,a4=0,a5=0,a6=0,a7=0;
  #pragma unroll 2
  for (int k4 = k40; k4 < k40 + 32; k4++){
    float4 c4 = ld4(&lci[k4 << 2]);
    float4 pv = ld4(pjb + ((size_t)k4 << 12));
    float4 ov = ld4(pob + ((size_t)k4 << 11));
    float4 g4 = ld4(&lg[k4 << 2]);
    float4 b4 = ld4(&lb[k4 << 2]);
    float h[4] = {c4.x+pv.x+ov.x, c4.y+pv.y+ov.y, c4.z+pv.z+ov.z, c4.w+pv.w+ov.w};
    float gg[4] = {g4.x,g4.y,g4.z,g4.w};
    float bb[4] = {b4.x,b4.y,b4.z,b4.w};
    #pragma unroll
    for (int e = 0; e < 4; e++){
      float v = fast_tanh(fmaf((h[e]-mu)*rstd, gg[e], bb[e]));
      float4 w0 = ld4(&lwo[((k4<<2)+e)<<3]);
      float4 w1 = ld4(&lwo[(((k4<<2)+e)<<3)+4]);
      a0 = fmaf(v, w0.x, a0); a1 = fmaf(v, w0.y, a1);
      a2 = fmaf(v, w0.z, a2); a3 = fmaf(v, w0.w, a3);
      a4 = fmaf(v, w1.x, a4); a5 = fmaf(v, w1.y, a5);
      a6 = fmaf(v, w1.z, a6); a7 = fmaf(v, w1.w, a7);
    }
  }
  if (q){
    pacc[jj][0]=a0; pacc[jj][1]=a1; pacc[jj][2]=a2; pacc[jj][3]=a3;
    pacc[jj][4]=a4; pacc[jj][5]=a5; pacc[jj][6]=a6; pacc[jj][7]=a7;
  }
  __syncthreads();
  if (!q){
    a0 += pacc[jj][0]; a1 += pacc[jj][1]; a2 += pacc[jj][2]; a3 += pacc[jj][3];
    a4 += pacc[jj][4]; a5 += pacc[jj][5]; a6 += pacc[jj][6]; a7 += pacc[jj][7];
    float acc[8] = {a0,a1,a2,a3,a4,a5,a6,a7};
    bool vis = (i < len) && (j < len);
    float res[8];
    #pragma unroll
    for (int r = 0; r < 8; r++){
      float sc = (acc[r] + bo[r]) * (1.f/7.5f);
      res[r] = vis ? fast_tanh(sc)*7.5f : -64.f;
    }
    float* lp = out + (((size_t)bi << 8) + j)*8;
    st4(lp,     make_float4(res[0],res[1],res[2],res[3]));
    st4(lp + 4, make_float4(res[4],res[5],res[6],res[7]));
    if (j == i){
      float* rp = out + (size_t)B_*L_*L_*R_ + ((size_t)bi)*8;
      st4(rp,     make_float4(res[0],res[1],res[2],res[3]));
      st4(rp + 4, make_float4(res[4],res[5],res[6],res[7]));
    }
  }
}

// ---------------------------------------------------------------------------
extern "C" void kernel_launch(void* const* d_in, const int* in_sizes, int n_in,
                              void* d_out, int out_size, void* d_ws, size_t ws_size,
                              hipStream_t stream)
{
  const float* X      = (const float*)d_in[0];
  const float* conv_w = (const float*)d_in[1];
  const float* conv_b = (const float*)d_in[2];
  const float* Wc     = (const float*)d_in[3];
  const float* bc     = (const float*)d_in[4];
  const float* Wp     = (const float*)d_in[5];
  const float* bp     = (const float*)d_in[6];
  const float* Wcum   = (const float*)d_in[7];
  const float* bcum   = (const float*)d_in[8];
  const float* Wr     = (const float*)d_in[9];
  const float* br     = (const float*)d_in[10];
  const float* ln_g   = (const float*)d_in[11];
  const float* ln_b   = (const float*)d_in[12];
  const float* Wo     = (const float*)d_in[13];
  const float* bo     = (const float*)d_in[14];
  const unsigned char* mask = (const unsigned char*)d_in[15];
  float* out = (float*)d_out;

  char* base = (char*)d_ws;
  auto alloc = [&](size_t bytes){ char* p = base; base += (bytes + 255) & ~(size_t)255; return p; };
  int*    lengths = (int*)   alloc(64);
  __bf16* Xb_u    = (__bf16*)alloc(2097152);
  __bf16* Xb_m    = (__bf16*)alloc(2097152);
  __bf16* Wbc     = (__bf16*)alloc(18874368);
  __bf16* Wcum_b  = (__bf16*)alloc(524288);
  __bf16* Wc_b    = (__bf16*)alloc(524288);   // contiguous with Wp_b -> [512][1024]
  __bf16* Wp_b    = (__bf16*)alloc(524288);
  __bf16* Wr_b    = (__bf16*)alloc(524288);
  __bf16* pe_b    = (__bf16*)alloc(1046528);
  float*  ypart   = (float*) alloc(16777216); // 4 x [1024][1024] f32
  __bf16* hb_mid  = (__bf16*)alloc(2097152);
  __bf16* hb_fin  = (__bf16*)alloc(2097152);
  float*  cum     = (float*) alloc(1048576);
  float*  cp_lin  = (float*) alloc(2097152);  // [1024][512]
  float*  ci_c    = (float*) alloc(1048576);  // [b][i][256]
  float*  pj_t    = (float*) alloc(1048576);  // [k4][b][j][4]
  float*  pos_t   = (float*) alloc(524288);   // [k4][512 d][4]
  (void)Wp_b;

  float* h_out = out + (size_t)B_*L_*L_*R_ + (size_t)B_*L_*R_;

  k_lengths<<<1, 256, 0, stream>>>(mask, lengths);
  k_megaprep<<<4607, 256, 0, stream>>>(X, lengths, Xb_u, Xb_m, conv_w, Wbc,
                                       Wcum, Wc, Wp, Wr, Wcum_b, Wc_b, Wp_b, Wr_b, pe_b);

  // cum = X @ Wcum^T + bcum
  k_gemm_mfma<<<dim3(16,4), 256, 0, stream>>>(Xb_u, Wcum_b, bcum, bcum, cum, nullptr,
                                              B_*L_, D4_, D_);

  // conv stack (z-split x4, XCD swizzle, bias folded into LN)
  k_conv_mfma<<<1024, 256, 0, stream>>>(Xb_m,   Wbc, ypart, 0);
  k_ln_tanh_mid<<<B_*L_, 256, 0, stream>>>(ypart, conv_b,        lengths, hb_mid);
  k_conv_mfma<<<1024, 256, 0, stream>>>(hb_mid, Wbc, ypart, 1);
  k_ln_tanh_mid<<<B_*L_, 256, 0, stream>>>(ypart, conv_b + 1024, lengths, hb_mid);
  k_conv_mfma<<<1024, 256, 0, stream>>>(hb_mid, Wbc, ypart, 2);
  k_ln_tanh_fin<<<B_*L_, 256, 0, stream>>>(ypart, conv_b + 2048, h_out, hb_fin);

  // c_lin & p_lin fused (N=512); pos GEMM -> transposed-packed pos_t
  k_gemm_mfma<<<dim3(16,8), 256, 0, stream>>>(hb_fin, Wc_b, bc, bp, cp_lin, nullptr,
                                              B_*L_, 512, D_);
  k_gemm_mfma<<<dim3(8,4),  256, 0, stream>>>(pe_b, Wr_b, br, br, nullptr, pos_t,
                                              511, D4_, D_);

  // cumsum + fold
  k_combine<<<256, 256, 0, stream>>>(cum, cp_lin, lengths, ci_c, pj_t);

  // pairs (2 threads per pair)
  k_pairs<<<B_*L_*2, 256, 0, stream>>>(ci_c, pj_t, pos_t, ln_g, ln_b, Wo, bo, lengths, out);
}

// Round 7
// 193.952 us; speedup vs baseline: 9.0176x; 1.3548x over previous
//
#include <hip/hip_runtime.h>

#define B_ 4
#define L_ 256
#define D_ 1024
#define D4_ 256
#define R_ 8

typedef __attribute__((ext_vector_type(8))) __bf16 bf16x8;
typedef __attribute__((ext_vector_type(4))) __bf16 bf16x4;
typedef __attribute__((ext_vector_type(4))) float f32x4;

__device__ __forceinline__ float4 ld4(const float* p){ return *reinterpret_cast<const float4*>(p); }
__device__ __forceinline__ void st4(float* p, float4 v){ *reinterpret_cast<float4*>(p) = v; }

// tanh via hardware exp2: ~8 VALU ops, abs err ~1e-7
__device__ __forceinline__ float fast_tanh(float x){
  x = fminf(fmaxf(x, -9.f), 9.f);
  float e = exp2f(x * 2.885390081777927f);     // e^{2x}
  return (e - 1.f) * __builtin_amdgcn_rcpf(e + 1.f);
}

__device__ __forceinline__ unsigned pack_bf16(float a, float b){
  __bf16 x = (__bf16)a, y = (__bf16)b;
  unsigned short ux = __builtin_bit_cast(unsigned short, x);
  unsigned short uy = __builtin_bit_cast(unsigned short, y);
  return (unsigned)ux | ((unsigned)uy << 16);
}

// ---------------------------------------------------------------------------
// Mask decode, parallel: wave per b, lane covers 4 positions.
// ---------------------------------------------------------------------------
__global__ void k_lengths(const unsigned char* mask, int* lengths){
  int tid = threadIdx.x;
  int b = tid >> 6, lane = tid & 63;
  const unsigned int* w = (const unsigned int*)mask;
  unsigned int w0 = w[0];
  int stride = 1;
  if      (w0 == 0x01010101u) stride = 1;
  else if (w0 == 0x3F803F80u) stride = 2;
  else if (w0 == 0x3C003C00u) stride = 2;
  else if (w0 == 0x3F800000u) stride = 4;
  else if (w0 == 1u && w[1] == 1u) stride = 4;
  else if (w0 == 1u && w[1] == 0u) stride = 8;
  else if (w0 == 0u && w[1] == 0x3FF00000u) stride = 8;
  int c = 0;
  #pragma unroll
  for (int e = 0; e < 4; e++){
    int l = lane*4 + e;
    const unsigned char* p = mask + (size_t)(b*L_ + l)*stride;
    unsigned char nz = 0;
    for (int s = 0; s < stride; s++) nz |= p[s];
    c += (nz != 0) ? 1 : 0;
  }
  #pragma unroll
  for (int m = 1; m < 64; m <<= 1) c += __shfl_xor(c, m);
  if (lane == 0) lengths[b] = c;
}

// ---------------------------------------------------------------------------
// Mega-prep: [0,512) X->bf16 | [512,1024) linear weights | [1024,4096) conv_w
// | [4096,4607) PE table.
// ---------------------------------------------------------------------------
__global__ __launch_bounds__(256) void k_megaprep(
    const float* __restrict__ X, const int* __restrict__ lengths,
    __bf16* __restrict__ xu, __bf16* __restrict__ xm,
    const float* __restrict__ cw, __bf16* __restrict__ wbc,
    const float* __restrict__ w0, const float* __restrict__ w1,
    const float* __restrict__ w2, const float* __restrict__ w3,
    __bf16* __restrict__ o0, __bf16* __restrict__ o1,
    __bf16* __restrict__ o2, __bf16* __restrict__ o3,
    __bf16* __restrict__ pe)
{
  int blk = blockIdx.x, tid = threadIdx.x;
  if (blk < 512){
    int idx = blk*256 + tid;
    int row = idx >> 7, c8 = (idx & 127) << 3;
    int b = row >> 8, l = row & 255;
    bool keep = l < lengths[b];
    const float* src = X + ((size_t)row << 10) + c8;
    bf16x8 u, m;
    #pragma unroll
    for (int e = 0; e < 8; e++){
      float f = src[e];
      u[e] = (__bf16)f;
      m[e] = keep ? (__bf16)f : (__bf16)0.f;
    }
    *reinterpret_cast<bf16x8*>(xu + ((size_t)row<<10) + c8) = u;
    *reinterpret_cast<bf16x8*>(xm + ((size_t)row<<10) + c8) = m;
  } else if (blk < 1024){
    int sub = blk - 512;
    const float* src; __bf16* dst;
    switch (sub >> 7){
      case 0: src = w0; dst = o0; break;
      case 1: src = w1; dst = o1; break;
      case 2: src = w2; dst = o2; break;
      default: src = w3; dst = o3; break;
    }
    int idx = (sub & 127)*256 + tid;
    const float* p = src + (size_t)idx*8;
    bf16x8 v;
    #pragma unroll
    for (int e = 0; e < 8; e++) v[e] = (__bf16)p[e];
    *reinterpret_cast<bf16x8*>(dst + (size_t)idx*8) = v;
  } else if (blk < 4096){
    int idx = (blk - 1024)*256 + tid;
    int layer = idx / 262144;
    int rem = idx & 262143;
    int o = rem >> 8, c4 = (rem & 255) << 2;
    const float* src = cw + (((size_t)layer*1024 + o)*1024 + c4)*3;
    float4 f0 = ld4(src), f1 = ld4(src+4), f2 = ld4(src+8);
    float tv[3][4] = {
      {f0.x, f0.w, f1.z, f2.y},
      {f0.y, f1.x, f1.w, f2.z},
      {f0.z, f1.y, f2.x, f2.w}
    };
    #pragma unroll
    for (int t = 0; t < 3; t++){
      bf16x4 v;
      #pragma unroll
      for (int e = 0; e < 4; e++) v[e] = (__bf16)tv[t][e];
      *reinterpret_cast<bf16x4*>(wbc + ((size_t)(layer*3+t)*1024 + o)*1024 + c4) = v;
    }
  } else {
    int t = blk - 4096;
    float posv = (float)(255 - t);
    const float c = -9.210340371976184f / (float)D_;
    for (int m = tid; m < D_/2; m += 256){
      float div = __expf((float)(2*m) * c);
      float val = posv * div;
      pe[((size_t)t<<10) + 2*m]     = (__bf16)__sinf(val);
      pe[((size_t)t<<10) + 2*m + 1] = (__bf16)__cosf(val);
    }
  }
}

// ---------------------------------------------------------------------------
// MFMA GEMM tile body (64x64). Ct: optional transposed-packed store.
// ---------------------------------------------------------------------------
__device__ __forceinline__ void gemm_body(__bf16 (*As)[64], __bf16 (*Bs)[64],
                                          const __bf16* __restrict__ A,
                                          const __bf16* __restrict__ Bw,
                                          const float* __restrict__ bias,
                                          const float* __restrict__ bias2,
                                          float* __restrict__ C,
                                          float* __restrict__ Ct,
                                          int M, int N, int Kd,
                                          int row0, int col0, int tid)
{
  int lane = tid & 63, wave = tid >> 6;
  int wm = (wave >> 1) << 5, wn = (wave & 1) << 5;
  f32x4 acc[2][2] = {};
  for (int k0 = 0; k0 < Kd; k0 += 64){
    for (int idx = tid; idx < 512; idx += 256){
      int r = idx >> 3, c = idx & 7;
      int row = row0 + r;
      bf16x8 v = {};
      if (row < M) v = *reinterpret_cast<const bf16x8*>(A + (size_t)row*Kd + k0 + (c<<3));
      *reinterpret_cast<bf16x8*>(&As[r][(c ^ (r & 7)) << 3]) = v;
    }
    for (int idx = tid; idx < 512; idx += 256){
      int r = idx >> 3, c = idx & 7;
      bf16x8 v = *reinterpret_cast<const bf16x8*>(Bw + (size_t)(col0 + r)*Kd + k0 + (c<<3));
      *reinterpret_cast<bf16x8*>(&Bs[r][(c ^ (r & 7)) << 3]) = v;
    }
    __syncthreads();
    #pragma unroll
    for (int kk = 0; kk < 2; kk++){
      int kc = (kk << 2) + (lane >> 4);
      int ra0 = wm + (lane & 15), ra1 = ra0 + 16;
      int rb0 = wn + (lane & 15), rb1 = rb0 + 16;
      bf16x8 a0 = *reinterpret_cast<const bf16x8*>(&As[ra0][(kc ^ (ra0 & 7)) << 3]);
      bf16x8 a1 = *reinterpret_cast<const bf16x8*>(&As[ra1][(kc ^ (ra1 & 7)) << 3]);
      bf16x8 b0 = *reinterpret_cast<const bf16x8*>(&Bs[rb0][(kc ^ (rb0 & 7)) << 3]);
      bf16x8 b1 = *reinterpret_cast<const bf16x8*>(&Bs[rb1][(kc ^ (rb1 & 7)) << 3]);
      acc[0][0] = __builtin_amdgcn_mfma_f32_16x16x32_bf16(a0, b0, acc[0][0], 0, 0, 0);
      acc[0][1] = __builtin_amdgcn_mfma_f32_16x16x32_bf16(a0, b1, acc[0][1], 0, 0, 0);
      acc[1][0] = __builtin_amdgcn_mfma_f32_16x16x32_bf16(a1, b0, acc[1][0], 0, 0, 0);
      acc[1][1] = __builtin_amdgcn_mfma_f32_16x16x32_bf16(a1, b1, acc[1][1], 0, 0, 0);
    }
    __syncthreads();
  }
  #pragma unroll
  for (int mi = 0; mi < 2; mi++)
    #pragma unroll
    for (int ni = 0; ni < 2; ni++){
      int col = col0 + wn + (ni << 4) + (lane & 15);
      float bv = (col < 256) ? bias[col] : bias2[col - 256];
      int rowb = row0 + wm + (mi << 4) + ((lane >> 4) << 2);
      if (Ct){
        float* dst = Ct + ((size_t)(col >> 2) << 11) + (col & 3);
        #pragma unroll
        for (int e = 0; e < 4; e++){
          int row = rowb + e;
          if (row < M) dst[row << 2] = acc[mi][ni][e] + bv;
        }
      } else {
        #pragma unroll
        for (int e = 0; e < 4; e++){
          int row = rowb + e;
          if (row < M) C[(size_t)row*N + col] = acc[mi][ni][e] + bv;
        }
      }
    }
}

// ---------------------------------------------------------------------------
// Batched tail GEMMs: [0,64) cum | [64,192) c_lin/p_lin fused | [192,224) pos.
// ---------------------------------------------------------------------------
__global__ __launch_bounds__(256) void k_gemm3(
    const __bf16* __restrict__ Xb_u, const __bf16* __restrict__ Wcum_b,
    const float* __restrict__ bcum, float* __restrict__ cum,
    const __bf16* __restrict__ hb_fin, const __bf16* __restrict__ Wc_b,
    const float* __restrict__ bc, const float* __restrict__ bp,
    float* __restrict__ cp_lin,
    const __bf16* __restrict__ pe_b, const __bf16* __restrict__ Wr_b,
    const float* __restrict__ br, float* __restrict__ pos_t)
{
  __shared__ __align__(16) __bf16 As[64][64];
  __shared__ __align__(16) __bf16 Bs[64][64];
  int blk = blockIdx.x, tid = threadIdx.x;
  if (blk < 64){
    gemm_body(As, Bs, Xb_u, Wcum_b, bcum, bcum, cum, nullptr,
              1024, 256, 1024, (blk & 15) << 6, (blk >> 4) << 6, tid);
  } else if (blk < 192){
    int s = blk - 64;
    gemm_body(As, Bs, hb_fin, Wc_b, bc, bp, cp_lin, nullptr,
              1024, 512, 1024, (s & 15) << 6, (s >> 4) << 6, tid);
  } else {
    int s = blk - 192;
    gemm_body(As, Bs, pe_b, Wr_b, br, br, nullptr, pos_t,
              511, 256, 1024, (s & 7) << 6, (s >> 3) << 6, tid);
  }
}

// ---------------------------------------------------------------------------
// Conv layer, z-split x4 (256 channels each), XCD-contiguous block swizzle.
// Partials (no bias) stored as bf16 to yz.
// ---------------------------------------------------------------------------
__global__ __launch_bounds__(256) void k_conv_mfma(const __bf16* __restrict__ hb,
                                                   const __bf16* __restrict__ wbc,
                                                   __bf16* __restrict__ y, int layer)
{
  __shared__ __align__(16) __bf16 As[66][64];
  __shared__ __align__(16) __bf16 Bs[3][64][64];
  int tid = threadIdx.x;
  int lane = tid & 63, wave = tid >> 6;
  int wm = (wave >> 1) << 5, wn = (wave & 1) << 5;
  int n = blockIdx.x;
  int swz = (n & 7)*128 + (n >> 3);      // XCD k handles contiguous swz chunk
  int bx = swz & 15, oy = (swz >> 4) & 15, z = swz >> 8;
  int b = bx >> 2, l0 = (bx & 3) << 6;
  int o0 = oy << 6;
  f32x4 acc[2][2] = {};
  for (int cc = 0; cc < 4; cc++){
    int c0 = (z << 8) + (cc << 6);
    for (int idx = tid; idx < 528; idx += 256){
      int r = idx >> 3, c = idx & 7;
      int l = l0 - 1 + r;
      bf16x8 v = {};
      if (l >= 0 && l < L_)
        v = *reinterpret_cast<const bf16x8*>(hb + (((size_t)(b<<8) + l) << 10) + c0 + (c<<3));
      *reinterpret_cast<bf16x8*>(&As[r][(c ^ (r & 7)) << 3]) = v;
    }
    for (int idx = tid; idx < 1536; idx += 256){
      int t = idx >> 9, r = (idx >> 3) & 63, c = idx & 7;
      bf16x8 v = *reinterpret_cast<const bf16x8*>(
          wbc + ((size_t)((layer*3 + t) << 10) + o0 + r)*1024 + c0 + (c<<3));
      *reinterpret_cast<bf16x8*>(&Bs[t][r][(c ^ (r & 7)) << 3]) = v;
    }
    __syncthreads();
    #pragma unroll
    for (int t = 0; t < 3; t++){
      #pragma unroll
      for (int kk = 0; kk < 2; kk++){
        int kc = (kk << 2) + (lane >> 4);
        int ra0 = wm + (lane & 15) + t, ra1 = ra0 + 16;
        int rb0 = wn + (lane & 15),     rb1 = rb0 + 16;
        bf16x8 a0 = *reinterpret_cast<const bf16x8*>(&As[ra0][(kc ^ (ra0 & 7)) << 3]);
        bf16x8 a1 = *reinterpret_cast<const bf16x8*>(&As[ra1][(kc ^ (ra1 & 7)) << 3]);
        bf16x8 b0 = *reinterpret_cast<const bf16x8*>(&Bs[t][rb0][(kc ^ (rb0 & 7)) << 3]);
        bf16x8 b1 = *reinterpret_cast<const bf16x8*>(&Bs[t][rb1][(kc ^ (rb1 & 7)) << 3]);
        acc[0][0] = __builtin_amdgcn_mfma_f32_16x16x32_bf16(a0, b0, acc[0][0], 0, 0, 0);
        acc[0][1] = __builtin_amdgcn_mfma_f32_16x16x32_bf16(a0, b1, acc[0][1], 0, 0, 0);
        acc[1][0] = __builtin_amdgcn_mfma_f32_16x16x32_bf16(a1, b0, acc[1][0], 0, 0, 0);
        acc[1][1] = __builtin_amdgcn_mfma_f32_16x16x32_bf16(a1, b1, acc[1][1], 0, 0, 0);
      }
    }
    __syncthreads();
  }
  __bf16* yz = y + (size_t)z * 1048576;
  #pragma unroll
  for (int mi = 0; mi < 2; mi++)
    #pragma unroll
    for (int ni = 0; ni < 2; ni++){
      int col = o0 + wn + (ni << 4) + (lane & 15);
      #pragma unroll
      for (int e = 0; e < 4; e++){
        int rowl = wm + (mi << 4) + ((lane >> 4) << 2) + e;
        yz[(((size_t)(b<<8) + l0 + rowl) << 10) + col] = (__bf16)acc[mi][ni][e];
      }
    }
}

// ---------------------------------------------------------------------------
// LN(1024)+tanh over sum of 4 bf16 partials + bias.
// ---------------------------------------------------------------------------
__device__ __forceinline__ void ln_core4(const __bf16* y, const float* cb, int n, int tid,
                                         int lane, int wid, float* red,
                                         float4& v, float& mu, float& rstd){
  const __bf16* yr = y + ((size_t)n << 10) + tid*4;
  bf16x4 a0 = *reinterpret_cast<const bf16x4*>(yr);
  bf16x4 a1 = *reinterpret_cast<const bf16x4*>(yr + 1048576);
  bf16x4 a2 = *reinterpret_cast<const bf16x4*>(yr + 2097152);
  bf16x4 a3 = *reinterpret_cast<const bf16x4*>(yr + 3145728);
  float4 bb = ld4(cb + tid*4);
  v = make_float4((float)a0[0]+(float)a1[0]+(float)a2[0]+(float)a3[0]+bb.x,
                  (float)a0[1]+(float)a1[1]+(float)a2[1]+(float)a3[1]+bb.y,
                  (float)a0[2]+(float)a1[2]+(float)a2[2]+(float)a3[2]+bb.z,
                  (float)a0[3]+(float)a1[3]+(float)a2[3]+(float)a3[3]+bb.w);
  float s = v.x+v.y+v.z+v.w;
  #pragma unroll
  for (int m=1;m<64;m<<=1) s += __shfl_xor(s, m);
  if (lane == 0) red[wid] = s;
  __syncthreads();
  mu = (red[0]+red[1]+red[2]+red[3]) * (1.f/D_);
  float d0=v.x-mu, d1=v.y-mu, d2=v.z-mu, d3=v.w-mu;
  float ss = d0*d0+d1*d1+d2*d2+d3*d3;
  #pragma unroll
  for (int m=1;m<64;m<<=1) ss += __shfl_xor(ss, m);
  if (lane == 0) red[8+wid] = ss;
  __syncthreads();
  rstd = rsqrtf((red[8]+red[9]+red[10]+red[11]) * (1.f/D_) + 1e-5f);
}

__global__ __launch_bounds__(256) void k_ln_tanh_mid(const __bf16* __restrict__ y,
                                                     const float* __restrict__ cb,
                                                     const int* __restrict__ lengths,
                                                     __bf16* __restrict__ hb)
{
  __shared__ float red[16];
  int n = blockIdx.x;
  int tid = threadIdx.x, lane = tid & 63, wid = tid >> 6;
  float4 v; float mu, rstd;
  ln_core4(y, cb, n, tid, lane, wid, red, v, mu, rstd);
  int l = n & 255, b = n >> 8;
  float keep = (l < lengths[b]) ? 1.f : 0.f;
  bf16x4 o;
  o[0] = (__bf16)(fast_tanh((v.x-mu)*rstd) * keep);
  o[1] = (__bf16)(fast_tanh((v.y-mu)*rstd) * keep);
  o[2] = (__bf16)(fast_tanh((v.z-mu)*rstd) * keep);
  o[3] = (__bf16)(fast_tanh((v.w-mu)*rstd) * keep);
  *reinterpret_cast<bf16x4*>(hb + ((size_t)n<<10) + tid*4) = o;
}

__global__ __launch_bounds__(256) void k_ln_tanh_fin(const __bf16* __restrict__ y,
                                                     const float* __restrict__ cb,
                                                     float* __restrict__ hf,
                                                     __bf16* __restrict__ hb)
{
  __shared__ float red[16];
  int n = blockIdx.x;
  int tid = threadIdx.x, lane = tid & 63, wid = tid >> 6;
  float4 v; float mu, rstd;
  ln_core4(y, cb, n, tid, lane, wid, red, v, mu, rstd);
  float t0 = fast_tanh((v.x-mu)*rstd), t1 = fast_tanh((v.y-mu)*rstd);
  float t2 = fast_tanh((v.z-mu)*rstd), t3 = fast_tanh((v.w-mu)*rstd);
  st4(&hf[((size_t)n<<10) + tid*4], make_float4(t0,t1,t2,t3));
  bf16x4 o; o[0]=(__bf16)t0; o[1]=(__bf16)t1; o[2]=(__bf16)t2; o[3]=(__bf16)t3;
  *reinterpret_cast<bf16x4*>(hb + ((size_t)n<<10) + tid*4) = o;
}

// ---------------------------------------------------------------------------
// Combine: masked cumsum + fold. ci row-major; pj transposed-packed
// pjt[k4][b][j][4].
// ---------------------------------------------------------------------------
__global__ __launch_bounds__(256) void k_combine(const float* __restrict__ cum,
                                                 const float* __restrict__ cp,
                                                 const int* __restrict__ lengths,
                                                 float* __restrict__ ci,
                                                 float* __restrict__ pjt)
{
  int w = blockIdx.x*4 + (threadIdx.x >> 6);
  int lane = threadIdx.x & 63;
  int b = w >> 8, k = w & 255;
  int len = lengths[b];
  int rowbase = b << 8;
  float v[4], p[4];
  float run = 0.f;
  #pragma unroll
  for (int e = 0; e < 4; e++){
    int l = lane*4 + e;
    float x = cum[(((size_t)rowbase + l) << 8) + k];
    v[e] = (l >= len) ? x : 0.f;
    run += v[e]; p[e] = run;
  }
  float t = run, s = run;
  #pragma unroll
  for (int off = 1; off < 64; off <<= 1){
    float u = __shfl_up(s, off);
    if (lane >= off) s += u;
  }
  float excl = s - t;
  float total = __shfl(s, 63);
  float* pjb = pjt + (((size_t)((k >> 2)*4 + b)) << 10) + (k & 3);
  #pragma unroll
  for (int e = 0; e < 4; e++){
    int l = lane*4 + e;
    size_t row = rowbase + l;
    float f_ex = excl + p[e] - v[e];
    float b_in = total - (excl + p[e]);
    ci[(row << 8) + k] = cp[row*512 + k] + f_ex;
    pjb[l << 2] = cp[row*512 + 256 + k] - b_in;
  }
}

// ---------------------------------------------------------------------------
// Pair kernel v6: 2 threads per pair; h kept as packed bf16 in 64 VGPRs,
// so pass 2 has zero global loads and no h recompute.
// ---------------------------------------------------------------------------
__global__ __launch_bounds__(256) void k_pairs(const float* __restrict__ ci,
                                               const float* __restrict__ pjt,
                                               const float* __restrict__ post,
                                               const float* __restrict__ ln_g,
                                               const float* __restrict__ ln_b,
                                               const float* __restrict__ Wo,
                                               const float* __restrict__ bo,
                                               const int* __restrict__ lengths,
                                               float* __restrict__ out)
{
  __shared__ __align__(16) float lci[256];
  __shared__ __align__(16) float lg[256];
  __shared__ __align__(16) float lb[256];
  __shared__ __align__(16) float lwo[2048];      // [k][8]
  __shared__ float sred[512];                    // s / q partials
  __shared__ float pacc[128][9];                 // q=1 projection partials (+pad)

  int bid = blockIdx.x;
  int hlf = bid & 1;
  int bi = bid >> 1;                 // b*256 + i
  int b = bi >> 8, i = bi & 255;
  int tid = threadIdx.x;
  int jj = tid & 127, q = tid >> 7;
  int j = (hlf << 7) + jj;

  lci[tid] = ci[((size_t)bi << 8) + tid];
  lg[tid] = ln_g[tid];
  lb[tid] = ln_b[tid];
  for (int t = tid; t < 2048; t += 256) lwo[t] = Wo[((t & 7) << 8) + (t >> 3)];
  __syncthreads();

  int len = lengths[b];
  int d = i - j + 255;
  const float* pjb = pjt + ((size_t)b << 10) + (j << 2);
  const float* pob = post + ((size_t)d << 2);
  int k40 = q << 5;                  // 32 k4-groups per half

  // pass 1: stats over this thread's 128 channels; stash h as packed bf16
  unsigned hreg[64];
  float s = 0.f, qq = 0.f;
  #pragma unroll
  for (int u = 0; u < 32; u++){
    int k4 = k40 + u;
    float4 c4 = ld4(&lci[k4 << 2]);
    float4 pv = ld4(pjb + ((size_t)k4 << 12));
    float4 ov = ld4(pob + ((size_t)k4 << 11));
    float h0 = c4.x+pv.x+ov.x, h1 = c4.y+pv.y+ov.y;
    float h2 = c4.z+pv.z+ov.z, h3 = c4.w+pv.w+ov.w;
    s += h0+h1+h2+h3;
    qq = fmaf(h0,h0,qq); qq = fmaf(h1,h1,qq); qq = fmaf(h2,h2,qq); qq = fmaf(h3,h3,qq);
    hreg[2*u]   = pack_bf16(h0, h1);
    hreg[2*u+1] = pack_bf16(h2, h3);
  }
  sred[tid] = s;
  sred[256 + tid] = qq;
  __syncthreads();
  float st = s + sred[tid ^ 128];
  float qt = qq + sred[256 + (tid ^ 128)];
  float mu = st * (1.f/256.f);
  float rstd = rsqrtf(fmaf(-mu, mu, qt * (1.f/256.f)) + 1e-5f);

  // pass 2: unpack h, normalize + tanh + projection (no global loads)
  float a0=0,a1=0,a2=0,a3=0,a4=0,a5=0,a6=0,a7=0;
  #pragma unroll
  for (int u = 0; u < 32; u++){
    int k4 = k40 + u;
    float4 g4 = ld4(&lg[k4 << 2]);
    float4 b4 = ld4(&lb[k4 << 2]);
    unsigned ua = hreg[2*u], ub = hreg[2*u+1];
    float h[4] = {__uint_as_float(ua << 16), __uint_as_float(ua & 0xFFFF0000u),
                  __uint_as_float(ub << 16), __uint_as_float(ub & 0xFFFF0000u)};
    float gg[4] = {g4.x,g4.y,g4.z,g4.w};
    float bb[4] = {b4.x,b4.y,b4.z,b4.w};
    #pragma unroll
    for (int e = 0; e < 4; e++){
      float v = fast_tanh(fmaf((h[e]-mu)*rstd, gg[e], bb[e]));
      float4 w0 = ld4(&lwo[((k4<<2)+e)<<3]);
      float4 w1 = ld4(&lwo[(((k4<<2)+e)<<3)+4]);
      a0 = fmaf(v, w0.x, a0); a1 = fmaf(v, w0.y, a1);
      a2 = fmaf(v, w0.z, a2); a3 = fmaf(v, w0.w, a3);
      a4 = fmaf(v, w1.x, a4); a5 = fmaf(v, w1.y, a5);
      a6 = fmaf(v, w1.z, a6); a7 = fmaf(v, w1.w, a7);
    }
  }
  if (q){
    pacc[jj][0]=a0; pacc[jj][1]=a1; pacc[jj][2]=a2; pacc[jj][3]=a3;
    pacc[jj][4]=a4; pacc[jj][5]=a5; pacc[jj][6]=a6; pacc[jj][7]=a7;
  }
  __syncthreads();
  if (!q){
    a0 += pacc[jj][0]; a1 += pacc[jj][1]; a2 += pacc[jj][2]; a3 += pacc[jj][3];
    a4 += pacc[jj][4]; a5 += pacc[jj][5]; a6 += pacc[jj][6]; a7 += pacc[jj][7];
    float acc[8] = {a0,a1,a2,a3,a4,a5,a6,a7};
    bool vis = (i < len) && (j < len);
    float res[8];
    #pragma unroll
    for (int r = 0; r < 8; r++){
      float sc = (acc[r] + bo[r]) * (1.f/7.5f);
      res[r] = vis ? fast_tanh(sc)*7.5f : -64.f;
    }
    float* lp = out + (((size_t)bi << 8) + j)*8;
    st4(lp,     make_float4(res[0],res[1],res[2],res[3]));
    st4(lp + 4, make_float4(res[4],res[5],res[6],res[7]));
    if (j == i){
      float* rp = out + (size_t)B_*L_*L_*R_ + ((size_t)bi)*8;
      st4(rp,     make_float4(res[0],res[1],res[2],res[3]));
      st4(rp + 4, make_float4(res[4],res[5],res[6],res[7]));
    }
  }
}

// ---------------------------------------------------------------------------
extern "C" void kernel_launch(void* const* d_in, const int* in_sizes, int n_in,
                              void* d_out, int out_size, void* d_ws, size_t ws_size,
                              hipStream_t stream)
{
  const float* X      = (const float*)d_in[0];
  const float* conv_w = (const float*)d_in[1];
  const float* conv_b = (const float*)d_in[2];
  const float* Wc     = (const float*)d_in[3];
  const float* bc     = (const float*)d_in[4];
  const float* Wp     = (const float*)d_in[5];
  const float* bp     = (const float*)d_in[6];
  const float* Wcum   = (const float*)d_in[7];
  const float* bcum   = (const float*)d_in[8];
  const float* Wr     = (const float*)d_in[9];
  const float* br     = (const float*)d_in[10];
  const float* ln_g   = (const float*)d_in[11];
  const float* ln_b   = (const float*)d_in[12];
  const float* Wo     = (const float*)d_in[13];
  const float* bo     = (const float*)d_in[14];
  const unsigned char* mask = (const unsigned char*)d_in[15];
  float* out = (float*)d_out;

  char* base = (char*)d_ws;
  auto alloc = [&](size_t bytes){ char* p = base; base += (bytes + 255) & ~(size_t)255; return p; };
  int*    lengths = (int*)   alloc(64);
  __bf16* Xb_u    = (__bf16*)alloc(2097152);
  __bf16* Xb_m    = (__bf16*)alloc(2097152);
  __bf16* Wbc     = (__bf16*)alloc(18874368);
  __bf16* Wcum_b  = (__bf16*)alloc(524288);
  __bf16* Wc_b    = (__bf16*)alloc(524288);   // contiguous with Wp_b -> [512][1024]
  __bf16* Wp_b    = (__bf16*)alloc(524288);
  __bf16* Wr_b    = (__bf16*)alloc(524288);
  __bf16* pe_b    = (__bf16*)alloc(1046528);
  __bf16* ypart   = (__bf16*)alloc(8388608);  // 4 x [1024][1024] bf16 partials
  __bf16* hb_mid  = (__bf16*)alloc(2097152);
  __bf16* hb_fin  = (__bf16*)alloc(2097152);
  float*  cum     = (float*) alloc(1048576);
  float*  cp_lin  = (float*) alloc(2097152);  // [1024][512]
  float*  ci_c    = (float*) alloc(1048576);  // [b][i][256]
  float*  pj_t    = (float*) alloc(1048576);  // [k4][b][j][4]
  float*  pos_t   = (float*) alloc(524288);   // [k4][512 d][4]
  (void)Wp_b;

  float* h_out = out + (size_t)B_*L_*L_*R_ + (size_t)B_*L_*R_;

  k_lengths<<<1, 256, 0, stream>>>(mask, lengths);
  k_megaprep<<<4607, 256, 0, stream>>>(X, lengths, Xb_u, Xb_m, conv_w, Wbc,
                                       Wcum, Wc, Wp, Wr, Wcum_b, Wc_b, Wp_b, Wr_b, pe_b);

  // conv stack (z-split x4, XCD swizzle, bf16 partials, bias folded into LN)
  k_conv_mfma<<<1024, 256, 0, stream>>>(Xb_m,   Wbc, ypart, 0);
  k_ln_tanh_mid<<<B_*L_, 256, 0, stream>>>(ypart, conv_b,        lengths, hb_mid);
  k_conv_mfma<<<1024, 256, 0, stream>>>(hb_mid, Wbc, ypart, 1);
  k_ln_tanh_mid<<<B_*L_, 256, 0, stream>>>(ypart, conv_b + 1024, lengths, hb_mid);
  k_conv_mfma<<<1024, 256, 0, stream>>>(hb_mid, Wbc, ypart, 2);
  k_ln_tanh_fin<<<B_*L_, 256, 0, stream>>>(ypart, conv_b + 2048, h_out, hb_fin);

  // batched tail GEMMs: cum | c_lin/p_lin | pos
  k_gemm3<<<224, 256, 0, stream>>>(Xb_u, Wcum_b, bcum, cum,
                                   hb_fin, Wc_b, bc, bp, cp_lin,
                                   pe_b, Wr_b, br, pos_t);

  // cumsum + fold
  k_combine<<<256, 256, 0, stream>>>(cum, cp_lin, lengths, ci_c, pj_t);

  // pairs (2 threads per pair, h in regs)
  k_pairs<<<B_*L_*2, 256, 0, stream>>>(ci_c, pj_t, pos_t, ln_g, ln_b, Wo, bo, lengths, out);
}